// Round 11
// baseline (288.305 us; speedup 1.0000x reference)
//
#include <hip/hip_runtime.h>
#include <hip/hip_fp16.h>

#define NM 131072   // mol nodes
#define EM 524288   // mol edges
#define NG 4096     // graphs
#define DM 6        // mol in dim
#define NP 100000   // prot nodes
#define EP 1600000  // prot edges
#define DP 20       // prot in dim

static inline int cdiv(int a, int b){ return (a + b - 1) / b; }

__device__ __forceinline__ float leaky(float x){ return x > 0.f ? x : 0.2f * x; }

union H8 { float4 f4; __half2 h2[4]; };
union HF8 { float4 f4; _Float16 h[8]; };

typedef _Float16 f16x8 __attribute__((ext_vector_type(8)));
typedef float    f32x4 __attribute__((ext_vector_type(4)));

// ================= merged bucketed CSR build: mol-dst + prot-dst + prot-src =================
__global__ void k_hist2(const int* __restrict__ dstM, const int* __restrict__ dstP,
                        const int* __restrict__ srcP,
                        int* __restrict__ coarseM, int* __restrict__ coarseP,
                        int* __restrict__ coarseS){
    __shared__ int lh[512];
    int t = threadIdx.x;
    const int* dst; int* coarse; int K, E, base, chunk;
    if (blockIdx.x < 256)      { dst = dstM; coarse = coarseM; K = 512; E = EM; chunk = 2048; base = blockIdx.x * 2048; }
    else if (blockIdx.x < 647) { dst = dstP; coarse = coarseP; K = 391; E = EP; chunk = 4096; base = (blockIdx.x - 256) * 4096; }
    else                       { dst = srcP; coarse = coarseS; K = 391; E = EP; chunk = 4096; base = (blockIdx.x - 647) * 4096; }
    for (int i = t; i < K; i += 256) lh[i] = 0;
    __syncthreads();
    int end = min(base + chunk, E);
    for (int e = base + t; e < end; e += 256)
        atomicAdd(&lh[dst[e] >> 8], 1);
    __syncthreads();
    for (int i = t; i < K; i += 256)
        if (lh[i]) atomicAdd(&coarse[i], lh[i]);
}

// scan + (blocks 3,4) one-time global f16 weight transposes
__global__ void k_scan2(const int* __restrict__ coarseM, int* __restrict__ cstartM, int* __restrict__ cursorM,
                        const int* __restrict__ coarseP, int* __restrict__ cstartP, int* __restrict__ cursorP,
                        const int* __restrict__ coarseS, int* __restrict__ cstartS, int* __restrict__ cursorS,
                        const float* __restrict__ gcn_w1, const float* __restrict__ gcn_w2,
                        const float* __restrict__ gat_w1, const float* __restrict__ gat_w2,
                        __half* __restrict__ w1tGc, __half* __restrict__ w2tGc,
                        __half* __restrict__ w1tGg, __half* __restrict__ w2tGg){
    int t = threadIdx.x;
    if (blockIdx.x == 3) {
        for (int i = t; i < 2048; i += 512) { int colj = i >> 5, k = i & 31;
            w1tGc[i] = __float2half(k < DM ? gcn_w1[k * 64 + colj] : 0.f); }
        for (int i = t; i < 4096; i += 512) { int colj = i >> 6, k = i & 63;
            w2tGc[i] = __float2half(gcn_w2[k * 64 + colj]); }
        return;
    }
    if (blockIdx.x == 4) {
        for (int i = t; i < 2048; i += 512) { int colj = i >> 5, k = i & 31;
            w1tGg[i] = __float2half(k < DP ? gat_w1[k * 64 + colj] : 0.f); }
        for (int i = t; i < 4096; i += 512) { int colj = i >> 6, k = i & 63;
            w2tGg[i] = __float2half(gat_w2[k * 64 + colj]); }
        return;
    }
    const int* coarse; int* cstart; int* cursor; int K;
    if (blockIdx.x == 0)      { coarse = coarseM; cstart = cstartM; cursor = cursorM; K = 512; }
    else if (blockIdx.x == 1) { coarse = coarseP; cstart = cstartP; cursor = cursorP; K = 391; }
    else                      { coarse = coarseS; cstart = cstartS; cursor = cursorS; K = 391; }
    int lane = t & 63, wid = t >> 6;
    int v0 = (t < K) ? coarse[t] : 0;
    int v = v0;
    #pragma unroll
    for (int off = 1; off < 64; off <<= 1) {
        int x = __shfl_up(v, off, 64);
        if (lane >= off) v += x;
    }
    __shared__ int ws[8];
    if (lane == 63) ws[wid] = v;
    __syncthreads();
    int add = 0;
    for (int w = 0; w < wid; w++) add += ws[w];
    int excl = v + add - v0;
    if (t < K) { cstart[t] = excl; cursor[t] = excl; }
    if (t == K - 1) cstart[K] = excl + v0;
}

__global__ void k_part2(const int* __restrict__ eiM, int* __restrict__ cursorM, unsigned* __restrict__ bufM,
                        const int* __restrict__ eiP, int* __restrict__ cursorP, unsigned* __restrict__ bufP,
                        int* __restrict__ cursorS, unsigned* __restrict__ bufS){
    __shared__ int lh[512];
    __shared__ int lbase[512];
    const int* ei; int* cursor; unsigned* buf; int E, K, base, sw;
    if (blockIdx.x < 128)      { ei = eiM; cursor = cursorM; buf = bufM; E = EM; K = 512; base = blockIdx.x * 4096; sw = 0; }
    else if (blockIdx.x < 519) { ei = eiP; cursor = cursorP; buf = bufP; E = EP; K = 391; base = (blockIdx.x - 128) * 4096; sw = 0; }
    else                       { ei = eiP; cursor = cursorS; buf = bufS; E = EP; K = 391; base = (blockIdx.x - 519) * 4096; sw = 1; }
    int t = threadIdx.x;
    for (int i = t; i < K; i += 256) lh[i] = 0;
    __syncthreads();
    int end = min(base + 4096, E);
    unsigned pay[16]; int bslot[16];
    int cnt = 0;
    for (int e = base + t; e < end; e += 256) {
        int u = ei[e], v = ei[E + e];
        int key = sw ? u : v, oth = sw ? v : u;
        int b = key >> 8;
        int ls = atomicAdd(&lh[b], 1);
        pay[cnt] = ((unsigned)(key & 255) << 24) | (unsigned)oth;
        bslot[cnt] = (b << 13) | ls;
        cnt++;
    }
    __syncthreads();
    for (int i = t; i < K; i += 256)
        lbase[i] = lh[i] ? atomicAdd(&cursor[i], lh[i]) : 0;
    __syncthreads();
    for (int j = 0; j < cnt; j++) {
        int b = bslot[j] >> 13, ls = bslot[j] & 8191;
        buf[lbase[b] + ls] = pay[j];
    }
}

// fine pass + fused prep epilogue (molprep+segbounds in mol blocks; prot prep in prot-dst blocks)
__global__ void k_fine2(const unsigned* __restrict__ bufM, const int* __restrict__ cstartM,
                        int* __restrict__ molRP, int* __restrict__ molCOL, float* __restrict__ dinv,
                        const unsigned* __restrict__ bufP, const int* __restrict__ cstartP,
                        int* __restrict__ protRP, int* __restrict__ protCOL,
                        const unsigned* __restrict__ bufS, const int* __restrict__ cstartS,
                        int* __restrict__ srcRP, int* __restrict__ srcCOL,
                        const float* __restrict__ mol_x, __half* __restrict__ x8,
                        const int* __restrict__ batch, int* __restrict__ gstart,
                        int* __restrict__ gend,
                        const float* __restrict__ prot_x, const float* __restrict__ W1a,
                        const float* __restrict__ as_, const float* __restrict__ ad_,
                        __half* __restrict__ x32, float* __restrict__ es,
                        float* __restrict__ ed_){
    __shared__ float vas[20], vds[20];
    int t = threadIdx.x;
    int k; const unsigned* buf; const int* cstart; int* rp; int* col; int n, OB, dv, pp;
    if (blockIdx.x < 512)      { k = blockIdx.x;       buf = bufM; cstart = cstartM; rp = molRP;  col = molCOL;  n = NM; OB = 20; dv = 1; pp = 0; }
    else if (blockIdx.x < 903) { k = blockIdx.x - 512; buf = bufP; cstart = cstartP; rp = protRP; col = protCOL; n = NP; OB = 21; dv = 0; pp = 1; }
    else                       { k = blockIdx.x - 903; buf = bufS; cstart = cstartS; rp = srcRP;  col = srcCOL;  n = NP; OB = 21; dv = 0; pp = 0; }
    if (pp) {
        if (t < 20) {
            float s = 0.f;
            for (int j = 0; j < 64; j++) s += W1a[t * 64 + j] * as_[j];
            vas[t] = s;
        } else if (t >= 32 && t < 52) {
            int kk = t - 32;
            float s = 0.f;
            for (int j = 0; j < 64; j++) s += W1a[kk * 64 + j] * ad_[j];
            vds[kk] = s;
        }
    }
    int start = cstart[k], end = cstart[k + 1];
    __shared__ int cnt[256];
    __shared__ int cur[256];
    cnt[t] = 0;
    __syncthreads();
    for (int p = start + t; p < end; p += 256)
        atomicAdd(&cnt[buf[p] >> 24], 1);
    __syncthreads();
    int v0 = cnt[t];
    int lane = t & 63, wid = t >> 6;
    int v = v0;
    #pragma unroll
    for (int off = 1; off < 64; off <<= 1) {
        int x = __shfl_up(v, off, 64);
        if (lane >= off) v += x;
    }
    __shared__ int ws[4];
    if (lane == 63) ws[wid] = v;
    __syncthreads();
    int add = 0;
    for (int w = 0; w < wid; w++) add += ws[w];
    int excl = v + add - v0;
    int ofs = start + excl;
    cur[t] = ofs;
    int idx = (k << 8) + t;
    if (idx < n) {
        rp[idx] = (int)((unsigned)ofs | ((unsigned)v0 << OB));
        if (dv) dinv[idx] = rsqrtf((float)(v0 + 1));
    }
    __syncthreads();
    for (int p = start + t; p < end; p += 256) {
        unsigned pk = buf[p];
        int slot = atomicAdd(&cur[pk >> 24], 1);
        col[slot] = (int)(pk & 0xFFFFFFu);
    }
    // ---- fused prep epilogue ----
    if (dv) {
        float dd = rsqrtf((float)(v0 + 1));
        H8 r;
        #pragma unroll
        for (int kk = 0; kk < 3; kk++)
            r.h2[kk] = __floats2half2_rn(dd * mol_x[idx*6 + 2*kk], dd * mol_x[idx*6 + 2*kk + 1]);
        r.h2[3] = __floats2half2_rn(0.f, 0.f);
        *(float4*)&x8[(size_t)idx * 8] = r.f4;
        int g = batch[idx];
        if (idx == 0 || batch[idx - 1] != g) gstart[g] = idx;
        if (idx == NM - 1 || batch[idx + 1] != g) gend[g] = idx + 1;
    } else if (pp && idx < n) {
        float xv[20];
        float s = 0.f, d = 0.f;
        #pragma unroll
        for (int kk = 0; kk < 20; kk++) {
            xv[kk] = prot_x[idx*20 + kk];
            s += xv[kk] * vas[kk]; d += xv[kk] * vds[kk];
        }
        es[idx] = s; ed_[idx] = d;
        H8 r0, r1, r2, rz;
        #pragma unroll
        for (int kk = 0; kk < 4; kk++) r0.h2[kk] = __floats2half2_rn(xv[2*kk],   xv[2*kk+1]);
        #pragma unroll
        for (int kk = 0; kk < 4; kk++) r1.h2[kk] = __floats2half2_rn(xv[8+2*kk], xv[9+2*kk]);
        r2.h2[0] = __floats2half2_rn(xv[16], xv[17]);
        r2.h2[1] = __floats2half2_rn(xv[18], xv[19]);
        r2.h2[2] = __floats2half2_rn(0.f, 0.f);
        r2.h2[3] = __floats2half2_rn(0.f, 0.f);
        rz.h2[0] = rz.h2[1] = rz.h2[2] = rz.h2[3] = __floats2half2_rn(0.f, 0.f);
        *(float4*)&x32[(size_t)idx * 32]      = r0.f4;
        *(float4*)&x32[(size_t)idx * 32 + 8]  = r1.f4;
        *(float4*)&x32[(size_t)idx * 32 + 16] = r2.f4;
        *(float4*)&x32[(size_t)idx * 32 + 24] = rz.f4;
    }
}

// ================= fused L1 gather + MLP, barrier-free (weights from global f16) ==========
// LDS (halves): Ain [4][16][40] @0, X1 [4][16][72] @2560 — all wave-local slabs.
// 14336 B, no __syncthreads anywhere: waves progress independently (no gather convoy).
// B-fragments (W1T/W2T) read straight from pre-transposed global (24 KB total, L1-hot).
template<int D, int ATT, int SCALE>
__device__ __forceinline__ void l1m_body(__half* smemh, int bid, int tid,
                                         const int* __restrict__ rp, const int* __restrict__ col,
                                         const __half* __restrict__ xrow,
                                         const float* __restrict__ es1, const float* __restrict__ ed1,
                                         const __half* __restrict__ w1tG, const float* __restrict__ b1,
                                         const __half* __restrict__ w2tG,
                                         const float* __restrict__ as_, const float* __restrict__ ad_,
                                         __half* __restrict__ hout, float* __restrict__ esO,
                                         float* __restrict__ edO, const float* __restrict__ dinv,
                                         int n){
    __half* AinS = smemh;            // 2560 halves (4 waves * 640)
    __half* X1S  = smemh + 2560;     // 4608 halves (4 waves * 1152)
    int lane = tid & 63, w = tid >> 6;
    int c = lane & 15, g = lane >> 4;
    int node0 = bid * 64 + w * 16;

    // ---- zero own wave's AinS slab ----
    {
        float4 z4 = make_float4(0.f, 0.f, 0.f, 0.f);
        float4* az = (float4*)(AinS + w * 640);
        for (int i = lane; i < 80; i += 64) az[i] = z4;
    }

    // ---- L1 gather straight into AinS (wave-local) ----
    if (!ATT) {
        // mol GCN: 16 nodes/wave, 4 lanes/node (edge slots)
        int nd = lane >> 2, q = lane & 3;
        int node = node0 + nd;
        unsigned pk = (unsigned)rp[node];
        int s0 = (int)(pk & 0xFFFFFu);
        int deg = (int)(pk >> 20);
        float acc[6] = {0.f,0.f,0.f,0.f,0.f,0.f};
        if (q == 0) {
            HF8 r; r.f4 = *(const float4*)&xrow[(size_t)node * 8];
            #pragma unroll
            for (int i = 0; i < 6; i++) acc[i] = (float)r.h[i];
        }
        for (int base = 0; base < deg; base += 4) {
            int s = base + q;
            if (s < deg) {
                int cc = col[s0 + s];
                HF8 r; r.f4 = *(const float4*)&xrow[(size_t)cc * 8];
                #pragma unroll
                for (int i = 0; i < 6; i++) acc[i] += (float)r.h[i];
            }
        }
        #pragma unroll
        for (int m = 1; m < 4; m <<= 1) {
            #pragma unroll
            for (int i = 0; i < 6; i++) acc[i] += __shfl_xor(acc[i], m, 64);
        }
        if (q == 0) {
            float dd = dinv[node];
            #pragma unroll
            for (int k = 0; k < 6; k++)
                AinS[w * 640 + nd * 40 + k] = __float2half(dd * acc[k]);
        }
    } else {
        // prot GAT: 4 rounds of {4 nodes x (4 slots x 4 chunks)}
        int nd4 = lane >> 4;
        int slot = (lane >> 2) & 3;
        int chunk = lane & 3;
        for (int rr = 0; rr < 4; rr++) {
            int row = rr * 4 + nd4;
            int node = node0 + row;
            bool valid = node < n;
            int nodeC = valid ? node : 0;
            unsigned pk = (unsigned)rp[nodeC];
            int s0 = (int)(pk & 0x1FFFFFu);
            int deg = valid ? (int)(pk >> 21) : 0;
            float edv = ed1[nodeC];
            float selfw = __expf(leaky(es1[nodeC] + edv));
            float acc[8] = {0.f,0.f,0.f,0.f,0.f,0.f,0.f,0.f};
            float den = (slot == 0) ? selfw : 0.f;
            if (slot == 0 && valid) {
                HF8 r; r.f4 = *(const float4*)&xrow[(size_t)node * 32 + (chunk << 3)];
                #pragma unroll
                for (int i = 0; i < 8; i++) acc[i] = selfw * (float)r.h[i];
            }
            for (int base = 0; base < deg; base += 4) {
                int s = base + slot;
                if (s < deg) {
                    int u = col[s0 + s];
                    float ww = __expf(leaky(es1[u] + edv));
                    HF8 r; r.f4 = *(const float4*)&xrow[(size_t)u * 32 + (chunk << 3)];
                    #pragma unroll
                    for (int i = 0; i < 8; i++) acc[i] += ww * (float)r.h[i];
                    den += ww;
                }
            }
            #pragma unroll
            for (int m = 4; m <= 8; m <<= 1) {
                #pragma unroll
                for (int i = 0; i < 8; i++) acc[i] += __shfl_xor(acc[i], m, 64);
                den += __shfl_xor(den, m, 64);
            }
            float inv = 1.f / den;
            if (slot == 0 && valid) {
                #pragma unroll
                for (int i = 0; i < 8; i++) {
                    int k = (chunk << 3) + i;
                    if (k < 20) AinS[w * 640 + row * 40 + k] = __float2half(acc[i] * inv);
                }
            }
        }
    }
    // no barrier: AinS slab is wave-local; within-wave LDS ordering is program-order

    // ---- layer 1 (B fragments from global W1T, L1-hot) ----
    f32x4 zz = {0.f, 0.f, 0.f, 0.f};
    f16x8 a1 = *(const f16x8*)&AinS[w * 640 + c * 40 + 8 * g];
    #pragma unroll
    for (int t = 0; t < 4; t++) {
        f16x8 b = *(const f16x8*)&w1tG[(16 * t + c) * 32 + 8 * g];
        f32x4 h = __builtin_amdgcn_mfma_f32_16x16x32_f16(a1, b, zz, 0, 0, 0);
        float bv = b1[16 * t + c];
        #pragma unroll
        for (int r = 0; r < 4; r++) {
            float v = fmaxf(h[r] + bv, 0.f);
            X1S[w * 1152 + (4 * g + r) * 72 + 16 * t + c] = __float2half(v);
        }
    }

    // ---- layer 2 (B fragments from global W2T) ----
    f32x4 acc2[4];
    #pragma unroll
    for (int t = 0; t < 4; t++) acc2[t] = zz;
    #pragma unroll
    for (int kt = 0; kt < 2; kt++) {
        f16x8 a = *(const f16x8*)&X1S[w * 1152 + c * 72 + 32 * kt + 8 * g];
        #pragma unroll
        for (int t = 0; t < 4; t++) {
            f16x8 b = *(const f16x8*)&w2tG[(16 * t + c) * 64 + 32 * kt + 8 * g];
            acc2[t] = __builtin_amdgcn_mfma_f32_16x16x32_f16(a, b, acc2[t], 0, 0, 0);
        }
    }

    if (ATT) {
        float asv[4], adv[4];
        #pragma unroll
        for (int t = 0; t < 4; t++) { asv[t] = as_[16 * t + c]; adv[t] = ad_[16 * t + c]; }
        #pragma unroll
        for (int r = 0; r < 4; r++) {
            float xa = 0.f, ya = 0.f;
            #pragma unroll
            for (int t = 0; t < 4; t++) { xa += acc2[t][r] * asv[t]; ya += acc2[t][r] * adv[t]; }
            #pragma unroll
            for (int m = 1; m < 16; m <<= 1) { xa += __shfl_xor(xa, m, 16); ya += __shfl_xor(ya, m, 16); }
            int nd = node0 + 4 * g + r;
            if (c == 0 && nd < n) { esO[nd] = xa; edO[nd] = ya; }
        }
    }
    if (SCALE) {
        #pragma unroll
        for (int r = 0; r < 4; r++) {
            float dd = dinv[node0 + 4 * g + r];
            #pragma unroll
            for (int t = 0; t < 4; t++) acc2[t][r] *= dd;
        }
    }

    // ---- repack through X1S (wave-local) -> coalesced float4 f16 stores ----
    #pragma unroll
    for (int t = 0; t < 4; t++) {
        #pragma unroll
        for (int r = 0; r < 4; r++)
            X1S[w * 1152 + (4 * g + r) * 72 + 16 * t + c] = __float2half(acc2[t][r]);
    }
    int rr2 = lane >> 2, seg = lane & 3;
    union { f16x8 h; float4 f; } o;
    o.h = *(const f16x8*)&X1S[w * 1152 + rr2 * 72 + seg * 16];
    int nd = node0 + rr2;
    if (!ATT || nd < n)
        *(float4*)&hout[(size_t)nd * 64 + seg * 16] = o.f;
}

#define PROTB 1563   // cdiv(NP, 64)

__global__ __launch_bounds__(256, 8)
void k_l1m(const int* __restrict__ molRP, const int* __restrict__ molCOL,
           const __half* __restrict__ x8, const float* __restrict__ dinvM,
           const __half* __restrict__ w1tGc, const float* __restrict__ gcn_b1,
           const __half* __restrict__ w2tGc, __half* __restrict__ h2hM,
           const int* __restrict__ protRP, const int* __restrict__ protCOL,
           const __half* __restrict__ x32, const float* __restrict__ es1,
           const float* __restrict__ ed1,
           const __half* __restrict__ w1tGg, const float* __restrict__ gat_b1,
           const __half* __restrict__ w2tGg,
           const float* __restrict__ as2, const float* __restrict__ ad2,
           __half* __restrict__ h2hP, float* __restrict__ es2, float* __restrict__ ed2){
    __shared__ __attribute__((aligned(16))) __half smemh[7168];   // 14336 B, barrier-free
    if (blockIdx.x < PROTB)   // long prot blocks first (LPT)
        l1m_body<20, 1, 0>(smemh, blockIdx.x, threadIdx.x, protRP, protCOL, x32, es1, ed1,
                           w1tGg, gat_b1, w2tGg, as2, ad2,
                           h2hP, es2, ed2, nullptr, NP);
    else
        l1m_body<6, 0, 1>(smemh, blockIdx.x - PROTB, threadIdx.x, molRP, molCOL, x8, nullptr, nullptr,
                          w1tGc, gcn_b1, w2tGc, nullptr, nullptr,
                          h2hM, nullptr, nullptr, dinvM, NM);
}

// ================= prot den (dst-CSR, es2-only gather) =================
__global__ void k_den(const int* __restrict__ protRP, const int* __restrict__ protCOL,
                      const float* __restrict__ es, const float* __restrict__ ed_,
                      float2* __restrict__ denEd){
    int tid = threadIdx.x;
    int node = (blockIdx.x << 4) + (tid >> 4);
    int l16 = tid & 15;
    unsigned pk = (unsigned)protRP[node];
    int s0 = (int)(pk & 0x1FFFFFu);
    int deg = (int)(pk >> 21);
    float edv = ed_[node];
    float den = 0.f;
    for (int s = l16; s < deg; s += 16) {
        int u = protCOL[s0 + s];
        den += __expf(leaky(es[u] + edv));
    }
    #pragma unroll
    for (int m = 1; m < 16; m <<= 1) den += __shfl_xor(den, m, 16);
    if (l16 == 0) {
        float selfw = __expf(leaky(es[node] + edv));
        denEd[node] = make_float2(1.f / (den + selfw), edv);
    }
}

// ================= merged L2: mol gather+pool (8192 blocks) + prot coef*row sum (3125 blocks) ==
__global__ void k_l2c(const int* __restrict__ molRP, const int* __restrict__ molCOL,
                      const __half* __restrict__ hhM, const float* __restrict__ dinv,
                      const int* __restrict__ batch, float* __restrict__ gsum,
                      const int* __restrict__ srcRP, const int* __restrict__ srcCOL,
                      const float* __restrict__ es, const float2* __restrict__ denEd,
                      const __half* __restrict__ hhP, float* __restrict__ psumP){
    __shared__ float sb[16][64];
    __shared__ int gidS[16];
    int tid = threadIdx.x;
    if (blockIdx.x < NM/16) {
        // mol L2: 16 nodes/block, 4 nodes/wave; per node: 2 edge-slots x 8 feature-chunks
        int bid = blockIdx.x;
        int wv = tid >> 6, l = tid & 63;
        int nd = l >> 4;
        int slot = (l >> 3) & 1;
        int q = l & 7;
        int node = (bid << 4) + (wv << 2) + nd;
        int row = (wv << 2) + nd;
        unsigned pk = (unsigned)molRP[node];
        int s0 = (int)(pk & 0xFFFFFu);
        int deg = (int)(pk >> 20);
        float acc[8] = {0.f,0.f,0.f,0.f,0.f,0.f,0.f,0.f};
        if (slot == 0) {
            HF8 r; r.f4 = *(const float4*)&hhM[(size_t)node * 64 + (q << 3)];
            #pragma unroll
            for (int i = 0; i < 8; i++) acc[i] = (float)r.h[i];
        }
        for (int base = 0; base < deg; base += 2) {
            int s = base + slot;
            if (s < deg) {
                int u = molCOL[s0 + s];
                HF8 r; r.f4 = *(const float4*)&hhM[(size_t)u * 64 + (q << 3)];
                #pragma unroll
                for (int i = 0; i < 8; i++) acc[i] += (float)r.h[i];
            }
        }
        #pragma unroll
        for (int i = 0; i < 8; i++) acc[i] += __shfl_xor(acc[i], 8, 64);
        if (slot == 0) {
            float sc = dinv[node];
            #pragma unroll
            for (int i = 0; i < 8; i++) sb[row][(q << 3) + i] = acc[i] * sc;
        }
        if (l == (nd << 4)) gidS[row] = batch[node];
        __syncthreads();
        if (tid < 64) {
            int i = 0;
            while (i < 16) {
                int g0 = gidS[i];
                float s = sb[i][tid];
                int j = i + 1;
                while (j < 16 && gidS[j] == g0) { s += sb[j][tid]; j++; }
                atomicAdd(&gsum[(g0 << 6) + tid], s);
                i = j;
            }
        }
    } else {
        // prot: per-source coef gather + coalesced weighted row accumulate
        int cb = blockIdx.x - NM/16;
        int wv = tid >> 6, l = tid & 63;
        int node = cb * 32 + (tid >> 3);
        int l8 = tid & 7;
        unsigned pk = (unsigned)srcRP[node];
        int s0 = (int)(pk & 0x1FFFFFu);
        int deg = (int)(pk >> 21);
        float esu = es[node];
        float sum = 0.f;
        for (int s = l8; s < deg; s += 8) {
            int v = srcCOL[s0 + s];
            float2 de = denEd[v];
            sum += __expf(leaky(esu + de.y)) * de.x;
        }
        #pragma unroll
        for (int m = 1; m < 8; m <<= 1) sum += __shfl_xor(sum, m, 8);
        float2 du = denEd[node];
        float coef = __expf(leaky(esu + du.y)) * du.x + sum;
        HF8 r; r.f4 = *(const float4*)&hhP[(size_t)node * 64 + (l8 << 3)];
        float acc[8];
        #pragma unroll
        for (int i = 0; i < 8; i++) acc[i] = coef * (float)r.h[i];
        #pragma unroll
        for (int m = 8; m <= 32; m <<= 1) {
            #pragma unroll
            for (int i = 0; i < 8; i++) acc[i] += __shfl_xor(acc[i], m, 64);
        }
        if ((l >> 3) == 0) {
            #pragma unroll
            for (int i = 0; i < 8; i++) sb[wv][(l8 << 3) + i] = acc[i];
        }
        __syncthreads();
        if (tid < 64) {
            float s = sb[0][tid] + sb[1][tid] + sb[2][tid] + sb[3][tid];
            atomicAdd(&psumP[((cb & 63) << 6) + tid], s);
        }
    }
}

// ---------------- fused classifier (reduces psumP, applies layer-2 biases) ----------------
__global__ void k_cls(const float* __restrict__ gsum, const int* __restrict__ gstart,
                      const int* __restrict__ gend, const float* __restrict__ psumP,
                      const float* __restrict__ bg, const float* __restrict__ bp,
                      const float* __restrict__ W1, const float* __restrict__ b1,
                      const float* __restrict__ w2, const float* __restrict__ b2,
                      float* __restrict__ out){
    __shared__ float W1s[128 * 64];
    __shared__ float pv[64], bgs[64];
    int tid = threadIdx.x;
    for (int k = tid; k < 128 * 64; k += 256) W1s[k] = W1[k];
    if (tid < 64) {
        float s = 0.f;
        for (int sl = 0; sl < 64; sl++) s += psumP[(sl << 6) + tid];
        pv[tid] = s * (1.0f / (float)NP) + bp[tid];
        bgs[tid] = bg[tid];
    }
    __syncthreads();
    int g = blockIdx.x * 4 + (tid >> 6);
    int j = tid & 63;
    float cntf = (float)(gend[g] - gstart[g]);
    float inv = 1.0f / fmaxf(cntf, 1.0f);
    float acc = b1[j];
    #pragma unroll 8
    for (int k = 0; k < 64; k++) acc += (gsum[g * 64 + k] * inv + bgs[k]) * W1s[k * 64 + j];
    #pragma unroll 8
    for (int k = 0; k < 64; k++) acc += pv[k] * W1s[(64 + k) * 64 + j];
    float v = fmaxf(acc, 0.f) * w2[j];
    #pragma unroll
    for (int off = 32; off > 0; off >>= 1) v += __shfl_down(v, off, 64);
    if (j == 0) out[g] = 1.0f / (1.0f + expf(-(v + b2[0])));
}

extern "C" void kernel_launch(void* const* d_in, const int* in_sizes, int n_in,
                              void* d_out, int out_size, void* d_ws, size_t ws_size,
                              hipStream_t stream) {
    const float* mol_x   = (const float*)d_in[0];
    const int*   mol_ei  = (const int*)d_in[1];
    const int*   mol_bat = (const int*)d_in[2];
    const float* prot_x  = (const float*)d_in[3];
    const int*   prot_ei = (const int*)d_in[4];
    const float* gcn_w1  = (const float*)d_in[5];
    const float* gcn_b1  = (const float*)d_in[6];
    const float* gcn_w2  = (const float*)d_in[7];
    const float* gcn_b2  = (const float*)d_in[8];
    const float* gat_w1  = (const float*)d_in[9];
    const float* gat_as1 = (const float*)d_in[10];
    const float* gat_ad1 = (const float*)d_in[11];
    const float* gat_b1  = (const float*)d_in[12];
    const float* gat_w2  = (const float*)d_in[13];
    const float* gat_as2 = (const float*)d_in[14];
    const float* gat_ad2 = (const float*)d_in[15];
    const float* gat_b2  = (const float*)d_in[16];
    const float* cls_w1  = (const float*)d_in[17];
    const float* cls_b1  = (const float*)d_in[18];
    const float* cls_w2  = (const float*)d_in[19];
    const float* cls_b2  = (const float*)d_in[20];
    float* out = (float*)d_out;

    float* ws_f = (float*)d_ws;

    // ---- persistent tail ----
    float* T       = ws_f + 16777216;
    float* gsum    = T;                       // 262,144 floats (zeroed)
    int*   gstart  = (int*)(T + 262144);      // 4,096 (zeroed)
    int*   gend    = (int*)(T + 266240);      // 4,096 (zeroed)
    int*   coarseM = (int*)(T + 270400);      // 512 (zeroed)
    int*   coarseP = (int*)(T + 270912);      // 512 (zeroed)
    int*   cstartM = (int*)(T + 271424);      // 513
    int*   cursorM = (int*)(T + 271937);      // 512
    int*   cstartP = (int*)(T + 272449);      // 513
    int*   cursorP = (int*)(T + 272962);      // 512
    float* psumP   = T + 273474;              // 64x64 (zeroed)
    int*   coarseS = (int*)(T + 277632);      // 512 (zeroed)
    int*   cstartS = (int*)(T + 278144);      // 513
    int*   cursorS = (int*)(T + 278657);      // 512  -> zeroed tail ends T+279,169
    __half* wTG    = (__half*)(T + 279200);   // 12,288 halves (w1tGc|w2tGc|w1tGg|w2tGg)
    __half* w1tGc  = wTG;                     // 2048
    __half* w2tGc  = wTG + 2048;              // 4096
    __half* w1tGg  = wTG + 6144;              // 2048
    __half* w2tGg  = wTG + 8192;              // 4096 -> ends T+285,344

    // ---- early CSR staging (dead after k_fine2) ----
    unsigned* bufM = (unsigned*)ws_f;                    // [0, 524,288)
    unsigned* bufP = (unsigned*)(ws_f + 524352);         // [524,352, 2,124,416)
    unsigned* bufS = (unsigned*)(ws_f + 2124480);        // [2,124,480, 3,724,480)

    // ---- overlapping phase regions (offsets in floats) ----
    __half*   h2hP      = (__half*)ws_f;
    int*      srcCOL    = (int*)(ws_f + 4194304);
    float*    es2       = ws_f + 5794304;
    float*    ed2       = ws_f + 5894304;
    float*    es1       = ws_f + 7794304;
    float*    ed1       = ws_f + 7894304;
    float2*   denEd     = (float2*)(ws_f + 7994304);
    int*      srcRP     = (int*)(ws_f + 8194304);
    __half*   h2hM      = (__half*)(ws_f + 8388608);
    int*      molCOL    = (int*)(ws_f + 12582912);       // EM+64 -> 13,107,264
    int*      molRP     = (int*)(ws_f + 13107264);       // NM -> 13,238,336 (+pad)
    float*    dinvM     = ws_f + 13238352;               // NM -> 13,369,424 (+pad)
    __half*   x8h       = (__half*)(ws_f + 13369440);    // NM*8 halves -> 13,893,728 (+pad)
    int*      protCOL   = (int*)(ws_f + 14680256);       // EP+64 -> 16,280,320
    int*      protRP    = (int*)(ws_f + 16280320);       // NP -> 16,380,320
    __half*   x32h      = (__half*)(ws_f + 17100000);    // NP*32 halves -> 18,700,000

    // single upfront zero of gsum..cursorS (contiguous tail region)
    (void)hipMemsetAsync(gsum, 0, (size_t)279169 * sizeof(float), stream);

    // ================= merged CSR build (mol-dst + prot-dst + prot-src) =================
    k_hist2<<<256 + 391 + 391, 256, 0, stream>>>(mol_ei + EM, prot_ei + EP, prot_ei,
                                                 coarseM, coarseP, coarseS);
    // scan + one-time global weight transposes (blocks 3,4)
    k_scan2<<<5, 512, 0, stream>>>(coarseM, cstartM, cursorM, coarseP, cstartP, cursorP,
                                   coarseS, cstartS, cursorS,
                                   gcn_w1, gcn_w2, gat_w1, gat_w2,
                                   w1tGc, w2tGc, w1tGg, w2tGg);
    k_part2<<<128 + 391 + 391, 256, 0, stream>>>(mol_ei, cursorM, bufM, prot_ei, cursorP, bufP,
                                                 cursorS, bufS);
    // fine pass + fused prep epilogue
    k_fine2<<<512 + 391 + 391, 256, 0, stream>>>(bufM, cstartM, molRP, molCOL, dinvM,
                                                 bufP, cstartP, protRP, protCOL,
                                                 bufS, cstartS, srcRP, srcCOL,
                                                 mol_x, x8h, mol_bat, gstart, gend,
                                                 prot_x, gat_w1, gat_as1, gat_ad1,
                                                 x32h, es1, ed1);

    // ================= fused L1 gather + MLP (barrier-free, prot-first LPT order) ==========
    k_l1m<<<PROTB + NM/64, 256, 0, stream>>>(molRP, molCOL, x8h, dinvM,
                                             w1tGc, gcn_b1, w2tGc, h2hM,
                                             protRP, protCOL, x32h, es1, ed1,
                                             w1tGg, gat_b1, w2tGg, gat_as2, gat_ad2,
                                             h2hP, es2, ed2);

    // ================= L2 phase: prot den -> (mol gather+pool || prot coef*row sum) =========
    k_den<<<NP/16, 256, 0, stream>>>(protRP, protCOL, es2, ed2, denEd);
    k_l2c<<<NM/16 + NP/32, 256, 0, stream>>>(molRP, molCOL, h2hM, dinvM, mol_bat, gsum,
                                             srcRP, srcCOL, es2, denEd, h2hP, psumP);

    // ================= classifier (reduces psumP, applies layer-2 biases) =================
    k_cls<<<NG/4, 256, 0, stream>>>(gsum, gstart, gend, psumP, gcn_b2, gat_b2,
                                    cls_w1, cls_b1, cls_w2, cls_b2, out);
}

// Round 12
// 281.621 us; speedup vs baseline: 1.0237x; 1.0237x over previous
//
#include <hip/hip_runtime.h>
#include <hip/hip_fp16.h>

#define NM 131072   // mol nodes
#define EM 524288   // mol edges
#define NG 4096     // graphs
#define DM 6        // mol in dim
#define NP 100000   // prot nodes
#define EP 1600000  // prot edges
#define DP 20       // prot in dim

static inline int cdiv(int a, int b){ return (a + b - 1) / b; }

__device__ __forceinline__ float leaky(float x){ return x > 0.f ? x : 0.2f * x; }

union H8 { float4 f4; __half2 h2[4]; };
union HF8 { float4 f4; _Float16 h[8]; };

typedef _Float16 f16x8 __attribute__((ext_vector_type(8)));
typedef float    f32x4 __attribute__((ext_vector_type(4)));

// ================= merged bucketed CSR build: mol-dst + prot-dst + prot-src =================
__global__ void k_hist2(const int* __restrict__ dstM, const int* __restrict__ dstP,
                        const int* __restrict__ srcP,
                        int* __restrict__ coarseM, int* __restrict__ coarseP,
                        int* __restrict__ coarseS){
    __shared__ int lh[512];
    int t = threadIdx.x;
    const int* dst; int* coarse; int K, E, base, chunk;
    if (blockIdx.x < 256)      { dst = dstM; coarse = coarseM; K = 512; E = EM; chunk = 2048; base = blockIdx.x * 2048; }
    else if (blockIdx.x < 647) { dst = dstP; coarse = coarseP; K = 391; E = EP; chunk = 4096; base = (blockIdx.x - 256) * 4096; }
    else                       { dst = srcP; coarse = coarseS; K = 391; E = EP; chunk = 4096; base = (blockIdx.x - 647) * 4096; }
    for (int i = t; i < K; i += 256) lh[i] = 0;
    __syncthreads();
    int end = min(base + chunk, E);
    for (int e = base + t; e < end; e += 256)
        atomicAdd(&lh[dst[e] >> 8], 1);
    __syncthreads();
    for (int i = t; i < K; i += 256)
        if (lh[i]) atomicAdd(&coarse[i], lh[i]);
}

// scan + (blocks 3,4) one-time f16 weight packing in EXACT k_l1m LDS layout:
// pack = [W2T 64x72 | W1T 64x40] halves (7168 per branch)
__global__ void k_scan2(const int* __restrict__ coarseM, int* __restrict__ cstartM, int* __restrict__ cursorM,
                        const int* __restrict__ coarseP, int* __restrict__ cstartP, int* __restrict__ cursorP,
                        const int* __restrict__ coarseS, int* __restrict__ cstartS, int* __restrict__ cursorS,
                        const float* __restrict__ gcn_w1, const float* __restrict__ gcn_w2,
                        const float* __restrict__ gat_w1, const float* __restrict__ gat_w2,
                        __half* __restrict__ wPackC, __half* __restrict__ wPackG){
    int t = threadIdx.x;
    if (blockIdx.x >= 3) {
        const float* W1 = (blockIdx.x == 3) ? gcn_w1 : gat_w1;
        const float* W2 = (blockIdx.x == 3) ? gcn_w2 : gat_w2;
        __half* wp = (blockIdx.x == 3) ? wPackC : wPackG;
        int D = (blockIdx.x == 3) ? DM : DP;
        for (int i = t; i < 4608; i += 512) {
            int colj = i / 72, k = i - colj * 72;
            wp[i] = __float2half(k < 64 ? W2[k * 64 + colj] : 0.f);
        }
        for (int i = t; i < 2560; i += 512) {
            int colj = i / 40, k = i - colj * 40;
            wp[4608 + i] = __float2half(k < D ? W1[k * 64 + colj] : 0.f);
        }
        return;
    }
    const int* coarse; int* cstart; int* cursor; int K;
    if (blockIdx.x == 0)      { coarse = coarseM; cstart = cstartM; cursor = cursorM; K = 512; }
    else if (blockIdx.x == 1) { coarse = coarseP; cstart = cstartP; cursor = cursorP; K = 391; }
    else                      { coarse = coarseS; cstart = cstartS; cursor = cursorS; K = 391; }
    int lane = t & 63, wid = t >> 6;
    int v0 = (t < K) ? coarse[t] : 0;
    int v = v0;
    #pragma unroll
    for (int off = 1; off < 64; off <<= 1) {
        int x = __shfl_up(v, off, 64);
        if (lane >= off) v += x;
    }
    __shared__ int ws[8];
    if (lane == 63) ws[wid] = v;
    __syncthreads();
    int add = 0;
    for (int w = 0; w < wid; w++) add += ws[w];
    int excl = v + add - v0;
    if (t < K) { cstart[t] = excl; cursor[t] = excl; }
    if (t == K - 1) cstart[K] = excl + v0;
}

__global__ void k_part2(const int* __restrict__ eiM, int* __restrict__ cursorM, unsigned* __restrict__ bufM,
                        const int* __restrict__ eiP, int* __restrict__ cursorP, unsigned* __restrict__ bufP,
                        int* __restrict__ cursorS, unsigned* __restrict__ bufS){
    __shared__ int lh[512];
    __shared__ int lbase[512];
    const int* ei; int* cursor; unsigned* buf; int E, K, base, sw;
    if (blockIdx.x < 128)      { ei = eiM; cursor = cursorM; buf = bufM; E = EM; K = 512; base = blockIdx.x * 4096; sw = 0; }
    else if (blockIdx.x < 519) { ei = eiP; cursor = cursorP; buf = bufP; E = EP; K = 391; base = (blockIdx.x - 128) * 4096; sw = 0; }
    else                       { ei = eiP; cursor = cursorS; buf = bufS; E = EP; K = 391; base = (blockIdx.x - 519) * 4096; sw = 1; }
    int t = threadIdx.x;
    for (int i = t; i < K; i += 256) lh[i] = 0;
    __syncthreads();
    int end = min(base + 4096, E);
    unsigned pay[16]; int bslot[16];
    int cnt = 0;
    for (int e = base + t; e < end; e += 256) {
        int u = ei[e], v = ei[E + e];
        int key = sw ? u : v, oth = sw ? v : u;
        int b = key >> 8;
        int ls = atomicAdd(&lh[b], 1);
        pay[cnt] = ((unsigned)(key & 255) << 24) | (unsigned)oth;
        bslot[cnt] = (b << 13) | ls;
        cnt++;
    }
    __syncthreads();
    for (int i = t; i < K; i += 256)
        lbase[i] = lh[i] ? atomicAdd(&cursor[i], lh[i]) : 0;
    __syncthreads();
    for (int j = 0; j < cnt; j++) {
        int b = bslot[j] >> 13, ls = bslot[j] & 8191;
        buf[lbase[b] + ls] = pay[j];
    }
}

// fine pass + fused prep epilogue (molprep+segbounds in mol blocks; prot prep in prot-dst blocks)
__global__ void k_fine2(const unsigned* __restrict__ bufM, const int* __restrict__ cstartM,
                        int* __restrict__ molRP, int* __restrict__ molCOL, float* __restrict__ dinv,
                        const unsigned* __restrict__ bufP, const int* __restrict__ cstartP,
                        int* __restrict__ protRP, int* __restrict__ protCOL,
                        const unsigned* __restrict__ bufS, const int* __restrict__ cstartS,
                        int* __restrict__ srcRP, int* __restrict__ srcCOL,
                        const float* __restrict__ mol_x, __half* __restrict__ x8,
                        const int* __restrict__ batch, int* __restrict__ gstart,
                        int* __restrict__ gend,
                        const float* __restrict__ prot_x, const float* __restrict__ W1a,
                        const float* __restrict__ as_, const float* __restrict__ ad_,
                        __half* __restrict__ x32, float* __restrict__ es,
                        float* __restrict__ ed_){
    __shared__ float vas[20], vds[20];
    int t = threadIdx.x;
    int k; const unsigned* buf; const int* cstart; int* rp; int* col; int n, OB, dv, pp;
    if (blockIdx.x < 512)      { k = blockIdx.x;       buf = bufM; cstart = cstartM; rp = molRP;  col = molCOL;  n = NM; OB = 20; dv = 1; pp = 0; }
    else if (blockIdx.x < 903) { k = blockIdx.x - 512; buf = bufP; cstart = cstartP; rp = protRP; col = protCOL; n = NP; OB = 21; dv = 0; pp = 1; }
    else                       { k = blockIdx.x - 903; buf = bufS; cstart = cstartS; rp = srcRP;  col = srcCOL;  n = NP; OB = 21; dv = 0; pp = 0; }
    if (pp) {
        if (t < 20) {
            float s = 0.f;
            for (int j = 0; j < 64; j++) s += W1a[t * 64 + j] * as_[j];
            vas[t] = s;
        } else if (t >= 32 && t < 52) {
            int kk = t - 32;
            float s = 0.f;
            for (int j = 0; j < 64; j++) s += W1a[kk * 64 + j] * ad_[j];
            vds[kk] = s;
        }
    }
    int start = cstart[k], end = cstart[k + 1];
    __shared__ int cnt[256];
    __shared__ int cur[256];
    cnt[t] = 0;
    __syncthreads();
    for (int p = start + t; p < end; p += 256)
        atomicAdd(&cnt[buf[p] >> 24], 1);
    __syncthreads();
    int v0 = cnt[t];
    int lane = t & 63, wid = t >> 6;
    int v = v0;
    #pragma unroll
    for (int off = 1; off < 64; off <<= 1) {
        int x = __shfl_up(v, off, 64);
        if (lane >= off) v += x;
    }
    __shared__ int ws[4];
    if (lane == 63) ws[wid] = v;
    __syncthreads();
    int add = 0;
    for (int w = 0; w < wid; w++) add += ws[w];
    int excl = v + add - v0;
    int ofs = start + excl;
    cur[t] = ofs;
    int idx = (k << 8) + t;
    if (idx < n) {
        rp[idx] = (int)((unsigned)ofs | ((unsigned)v0 << OB));
        if (dv) dinv[idx] = rsqrtf((float)(v0 + 1));
    }
    __syncthreads();
    for (int p = start + t; p < end; p += 256) {
        unsigned pk = buf[p];
        int slot = atomicAdd(&cur[pk >> 24], 1);
        col[slot] = (int)(pk & 0xFFFFFFu);
    }
    // ---- fused prep epilogue ----
    if (dv) {
        float dd = rsqrtf((float)(v0 + 1));
        H8 r;
        #pragma unroll
        for (int kk = 0; kk < 3; kk++)
            r.h2[kk] = __floats2half2_rn(dd * mol_x[idx*6 + 2*kk], dd * mol_x[idx*6 + 2*kk + 1]);
        r.h2[3] = __floats2half2_rn(0.f, 0.f);
        *(float4*)&x8[(size_t)idx * 8] = r.f4;
        int g = batch[idx];
        if (idx == 0 || batch[idx - 1] != g) gstart[g] = idx;
        if (idx == NM - 1 || batch[idx + 1] != g) gend[g] = idx + 1;
    } else if (pp && idx < n) {
        float xv[20];
        float s = 0.f, d = 0.f;
        #pragma unroll
        for (int kk = 0; kk < 20; kk++) {
            xv[kk] = prot_x[idx*20 + kk];
            s += xv[kk] * vas[kk]; d += xv[kk] * vds[kk];
        }
        es[idx] = s; ed_[idx] = d;
        H8 r0, r1, r2, rz;
        #pragma unroll
        for (int kk = 0; kk < 4; kk++) r0.h2[kk] = __floats2half2_rn(xv[2*kk],   xv[2*kk+1]);
        #pragma unroll
        for (int kk = 0; kk < 4; kk++) r1.h2[kk] = __floats2half2_rn(xv[8+2*kk], xv[9+2*kk]);
        r2.h2[0] = __floats2half2_rn(xv[16], xv[17]);
        r2.h2[1] = __floats2half2_rn(xv[18], xv[19]);
        r2.h2[2] = __floats2half2_rn(0.f, 0.f);
        r2.h2[3] = __floats2half2_rn(0.f, 0.f);
        rz.h2[0] = rz.h2[1] = rz.h2[2] = rz.h2[3] = __floats2half2_rn(0.f, 0.f);
        *(float4*)&x32[(size_t)idx * 32]      = r0.f4;
        *(float4*)&x32[(size_t)idx * 32 + 8]  = r1.f4;
        *(float4*)&x32[(size_t)idx * 32 + 16] = r2.f4;
        *(float4*)&x32[(size_t)idx * 32 + 24] = rz.f4;
    }
}

// ================= fused L1 gather + MLP (MFMA f16 16x16x32), 64 nodes/block, 4 waves =====
// LDS overlay (halves): W2T [64][72] @0, W1T [64][40] @4608, Ain [4][16][40] @7168,
//                       X1 [4][16][72] @4608 (overlays W1T+Ain after both are dead).
// 19456 B -> 8 blocks/CU. Weights staged by float4 copy from pre-packed global blob
// (coalesced reads, stride-1 LDS writes: conflict-free; MFMA reads stay in LDS).
template<int D, int ATT, int SCALE>
__device__ __forceinline__ void l1m_body(__half* smemh, int bid, int tid,
                                         const int* __restrict__ rp, const int* __restrict__ col,
                                         const __half* __restrict__ xrow,
                                         const float* __restrict__ es1, const float* __restrict__ ed1,
                                         const __half* __restrict__ wPack, const float* __restrict__ b1,
                                         const float* __restrict__ as_, const float* __restrict__ ad_,
                                         __half* __restrict__ hout, float* __restrict__ esO,
                                         float* __restrict__ edO, const float* __restrict__ dinv,
                                         int n){
    __half* W2Ts = smemh;            // 4608 halves @0
    __half* W1Ts = smemh + 4608;     // 2560 halves @4608
    __half* AinS = smemh + 7168;     // 2560 halves @7168 (4 waves * 640)
    __half* X1S  = smemh + 4608;     // 4608 halves overlay @4608
    int lane = tid & 63, w = tid >> 6;
    int c = lane & 15, g = lane >> 4;
    int node0 = bid * 64 + w * 16;

    // ---- stage packed weights: 7168 halves = 896 float4, coalesced, conflict-free ----
    {
        const float4* wp4 = (const float4*)wPack;
        float4* sm4 = (float4*)smemh;
        #pragma unroll
        for (int i = 0; i < 3; i++) sm4[tid + 256 * i] = wp4[tid + 256 * i];
        if (tid < 128) sm4[768 + tid] = wp4[768 + tid];
    }
    // ---- zero own wave's AinS slab ----
    {
        float4 z4 = make_float4(0.f, 0.f, 0.f, 0.f);
        float4* az = (float4*)(AinS + w * 640);
        for (int i = lane; i < 80; i += 64) az[i] = z4;
    }

    // ---- L1 gather straight into AinS ----
    if (!ATT) {
        // mol GCN: 16 nodes/wave, 4 lanes/node (edge slots)
        int nd = lane >> 2, q = lane & 3;
        int node = node0 + nd;
        unsigned pk = (unsigned)rp[node];
        int s0 = (int)(pk & 0xFFFFFu);
        int deg = (int)(pk >> 20);
        float acc[6] = {0.f,0.f,0.f,0.f,0.f,0.f};
        if (q == 0) {
            HF8 r; r.f4 = *(const float4*)&xrow[(size_t)node * 8];
            #pragma unroll
            for (int i = 0; i < 6; i++) acc[i] = (float)r.h[i];
        }
        for (int base = 0; base < deg; base += 4) {
            int s = base + q;
            if (s < deg) {
                int cc = col[s0 + s];
                HF8 r; r.f4 = *(const float4*)&xrow[(size_t)cc * 8];
                #pragma unroll
                for (int i = 0; i < 6; i++) acc[i] += (float)r.h[i];
            }
        }
        #pragma unroll
        for (int m = 1; m < 4; m <<= 1) {
            #pragma unroll
            for (int i = 0; i < 6; i++) acc[i] += __shfl_xor(acc[i], m, 64);
        }
        if (q == 0) {
            float dd = dinv[node];
            #pragma unroll
            for (int k = 0; k < 6; k++)
                AinS[w * 640 + nd * 40 + k] = __float2half(dd * acc[k]);
        }
    } else {
        // prot GAT: 4 rounds of {4 nodes x (4 slots x 4 chunks)}; chunk 3 covers only
        // zero-pad features (k>=24 never written) -> its loads/FMAs are dead, skip them.
        int nd4 = lane >> 4;
        int slot = (lane >> 2) & 3;
        int chunk = lane & 3;
        bool live = chunk < 3;
        for (int rr = 0; rr < 4; rr++) {
            int row = rr * 4 + nd4;
            int node = node0 + row;
            bool valid = node < n;
            int nodeC = valid ? node : 0;
            unsigned pk = (unsigned)rp[nodeC];
            int s0 = (int)(pk & 0x1FFFFFu);
            int deg = valid ? (int)(pk >> 21) : 0;
            float edv = ed1[nodeC];
            float selfw = __expf(leaky(es1[nodeC] + edv));
            float acc[8] = {0.f,0.f,0.f,0.f,0.f,0.f,0.f,0.f};
            float den = (slot == 0) ? selfw : 0.f;
            if (slot == 0 && valid && live) {
                HF8 r; r.f4 = *(const float4*)&xrow[(size_t)node * 32 + (chunk << 3)];
                #pragma unroll
                for (int i = 0; i < 8; i++) acc[i] = selfw * (float)r.h[i];
            }
            for (int base = 0; base < deg; base += 4) {
                int s = base + slot;
                if (s < deg) {
                    int u = col[s0 + s];
                    float ww = __expf(leaky(es1[u] + edv));
                    if (live) {
                        HF8 r; r.f4 = *(const float4*)&xrow[(size_t)u * 32 + (chunk << 3)];
                        #pragma unroll
                        for (int i = 0; i < 8; i++) acc[i] += ww * (float)r.h[i];
                    }
                    den += ww;
                }
            }
            #pragma unroll
            for (int m = 4; m <= 8; m <<= 1) {
                #pragma unroll
                for (int i = 0; i < 8; i++) acc[i] += __shfl_xor(acc[i], m, 64);
                den += __shfl_xor(den, m, 64);
            }
            float inv = 1.f / den;
            if (slot == 0 && valid && live) {
                #pragma unroll
                for (int i = 0; i < 8; i++) {
                    int k = (chunk << 3) + i;
                    if (k < 20) AinS[w * 640 + row * 40 + k] = __float2half(acc[i] * inv);
                }
            }
        }
    }
    __syncthreads();   // gather + weight staging complete

    // ---- layer 1: register-cache A and all W1T fragments, then sync, then MFMA+X1 write ----
    f32x4 zz = {0.f, 0.f, 0.f, 0.f};
    f16x8 a1 = *(const f16x8*)&AinS[w * 640 + c * 40 + 8 * g];
    f16x8 b1f[4];
    #pragma unroll
    for (int t = 0; t < 4; t++)
        b1f[t] = *(const f16x8*)&W1Ts[(16 * t + c) * 40 + 8 * g];
    __syncthreads();   // all W1Ts/AinS reads done -> X1S overlay may be written
    #pragma unroll
    for (int t = 0; t < 4; t++) {
        f32x4 h = __builtin_amdgcn_mfma_f32_16x16x32_f16(a1, b1f[t], zz, 0, 0, 0);
        float bv = b1[16 * t + c];
        #pragma unroll
        for (int r = 0; r < 4; r++) {
            float v = fmaxf(h[r] + bv, 0.f);
            X1S[w * 1152 + (4 * g + r) * 72 + 16 * t + c] = __float2half(v);
        }
    }
    // X1S slabs are wave-local: no block sync needed before layer 2

    // ---- layer 2 ----
    f32x4 acc2[4];
    #pragma unroll
    for (int t = 0; t < 4; t++) acc2[t] = zz;
    #pragma unroll
    for (int kt = 0; kt < 2; kt++) {
        f16x8 a = *(const f16x8*)&X1S[w * 1152 + c * 72 + 32 * kt + 8 * g];
        #pragma unroll
        for (int t = 0; t < 4; t++) {
            f16x8 b = *(const f16x8*)&W2Ts[(16 * t + c) * 72 + 32 * kt + 8 * g];
            acc2[t] = __builtin_amdgcn_mfma_f32_16x16x32_f16(a, b, acc2[t], 0, 0, 0);
        }
    }

    if (ATT) {
        float asv[4], adv[4];
        #pragma unroll
        for (int t = 0; t < 4; t++) { asv[t] = as_[16 * t + c]; adv[t] = ad_[16 * t + c]; }
        #pragma unroll
        for (int r = 0; r < 4; r++) {
            float xa = 0.f, ya = 0.f;
            #pragma unroll
            for (int t = 0; t < 4; t++) { xa += acc2[t][r] * asv[t]; ya += acc2[t][r] * adv[t]; }
            #pragma unroll
            for (int m = 1; m < 16; m <<= 1) { xa += __shfl_xor(xa, m, 16); ya += __shfl_xor(ya, m, 16); }
            int nd = node0 + 4 * g + r;
            if (c == 0 && nd < n) { esO[nd] = xa; edO[nd] = ya; }
        }
    }
    if (SCALE) {
        #pragma unroll
        for (int r = 0; r < 4; r++) {
            float dd = dinv[node0 + 4 * g + r];
            #pragma unroll
            for (int t = 0; t < 4; t++) acc2[t][r] *= dd;
        }
    }

    // ---- repack through X1S (wave-local) -> coalesced float4 f16 stores ----
    #pragma unroll
    for (int t = 0; t < 4; t++) {
        #pragma unroll
        for (int r = 0; r < 4; r++)
            X1S[w * 1152 + (4 * g + r) * 72 + 16 * t + c] = __float2half(acc2[t][r]);
    }
    int rr2 = lane >> 2, seg = lane & 3;
    union { f16x8 h; float4 f; } o;
    o.h = *(const f16x8*)&X1S[w * 1152 + rr2 * 72 + seg * 16];
    int nd = node0 + rr2;
    if (!ATT || nd < n)
        *(float4*)&hout[(size_t)nd * 64 + seg * 16] = o.f;
}

#define PROTB 1563   // cdiv(NP, 64)

__global__ __launch_bounds__(256, 8)
void k_l1m(const int* __restrict__ molRP, const int* __restrict__ molCOL,
           const __half* __restrict__ x8, const float* __restrict__ dinvM,
           const __half* __restrict__ wPackC, const float* __restrict__ gcn_b1,
           __half* __restrict__ h2hM,
           const int* __restrict__ protRP, const int* __restrict__ protCOL,
           const __half* __restrict__ x32, const float* __restrict__ es1,
           const float* __restrict__ ed1,
           const __half* __restrict__ wPackG, const float* __restrict__ gat_b1,
           const float* __restrict__ as2, const float* __restrict__ ad2,
           __half* __restrict__ h2hP, float* __restrict__ es2, float* __restrict__ ed2){
    __shared__ __attribute__((aligned(16))) __half smemh[9728];   // 19456 B -> 8 blocks/CU
    if (blockIdx.x < PROTB)   // long prot blocks first (LPT)
        l1m_body<20, 1, 0>(smemh, blockIdx.x, threadIdx.x, protRP, protCOL, x32, es1, ed1,
                           wPackG, gat_b1, as2, ad2,
                           h2hP, es2, ed2, nullptr, NP);
    else
        l1m_body<6, 0, 1>(smemh, blockIdx.x - PROTB, threadIdx.x, molRP, molCOL, x8, nullptr, nullptr,
                          wPackC, gcn_b1, nullptr, nullptr,
                          h2hM, nullptr, nullptr, dinvM, NM);
}

// ================= prot den (dst-CSR, es2-only gather) =================
__global__ void k_den(const int* __restrict__ protRP, const int* __restrict__ protCOL,
                      const float* __restrict__ es, const float* __restrict__ ed_,
                      float2* __restrict__ denEd){
    int tid = threadIdx.x;
    int node = (blockIdx.x << 4) + (tid >> 4);
    int l16 = tid & 15;
    unsigned pk = (unsigned)protRP[node];
    int s0 = (int)(pk & 0x1FFFFFu);
    int deg = (int)(pk >> 21);
    float edv = ed_[node];
    float den = 0.f;
    for (int s = l16; s < deg; s += 16) {
        int u = protCOL[s0 + s];
        den += __expf(leaky(es[u] + edv));
    }
    #pragma unroll
    for (int m = 1; m < 16; m <<= 1) den += __shfl_xor(den, m, 16);
    if (l16 == 0) {
        float selfw = __expf(leaky(es[node] + edv));
        denEd[node] = make_float2(1.f / (den + selfw), edv);
    }
}

// ================= merged L2: mol gather+pool (8192 blocks) + prot coef*row sum (3125 blocks) ==
__global__ void k_l2c(const int* __restrict__ molRP, const int* __restrict__ molCOL,
                      const __half* __restrict__ hhM, const float* __restrict__ dinv,
                      const int* __restrict__ batch, float* __restrict__ gsum,
                      const int* __restrict__ srcRP, const int* __restrict__ srcCOL,
                      const float* __restrict__ es, const float2* __restrict__ denEd,
                      const __half* __restrict__ hhP, float* __restrict__ psumP){
    __shared__ float sb[16][64];
    __shared__ int gidS[16];
    int tid = threadIdx.x;
    if (blockIdx.x < NM/16) {
        // mol L2: 16 nodes/block, 4 nodes/wave; per node: 2 edge-slots x 8 feature-chunks
        int bid = blockIdx.x;
        int wv = tid >> 6, l = tid & 63;
        int nd = l >> 4;
        int slot = (l >> 3) & 1;
        int q = l & 7;
        int node = (bid << 4) + (wv << 2) + nd;
        int row = (wv << 2) + nd;
        unsigned pk = (unsigned)molRP[node];
        int s0 = (int)(pk & 0xFFFFFu);
        int deg = (int)(pk >> 20);
        float acc[8] = {0.f,0.f,0.f,0.f,0.f,0.f,0.f,0.f};
        if (slot == 0) {
            HF8 r; r.f4 = *(const float4*)&hhM[(size_t)node * 64 + (q << 3)];
            #pragma unroll
            for (int i = 0; i < 8; i++) acc[i] = (float)r.h[i];
        }
        for (int base = 0; base < deg; base += 2) {
            int s = base + slot;
            if (s < deg) {
                int u = molCOL[s0 + s];
                HF8 r; r.f4 = *(const float4*)&hhM[(size_t)u * 64 + (q << 3)];
                #pragma unroll
                for (int i = 0; i < 8; i++) acc[i] += (float)r.h[i];
            }
        }
        #pragma unroll
        for (int i = 0; i < 8; i++) acc[i] += __shfl_xor(acc[i], 8, 64);
        if (slot == 0) {
            float sc = dinv[node];
            #pragma unroll
            for (int i = 0; i < 8; i++) sb[row][(q << 3) + i] = acc[i] * sc;
        }
        if (l == (nd << 4)) gidS[row] = batch[node];
        __syncthreads();
        if (tid < 64) {
            int i = 0;
            while (i < 16) {
                int g0 = gidS[i];
                float s = sb[i][tid];
                int j = i + 1;
                while (j < 16 && gidS[j] == g0) { s += sb[j][tid]; j++; }
                atomicAdd(&gsum[(g0 << 6) + tid], s);
                i = j;
            }
        }
    } else {
        // prot: per-source coef gather + coalesced weighted row accumulate
        int cb = blockIdx.x - NM/16;
        int wv = tid >> 6, l = tid & 63;
        int node = cb * 32 + (tid >> 3);
        int l8 = tid & 7;
        unsigned pk = (unsigned)srcRP[node];
        int s0 = (int)(pk & 0x1FFFFFu);
        int deg = (int)(pk >> 21);
        float esu = es[node];
        float sum = 0.f;
        for (int s = l8; s < deg; s += 8) {
            int v = srcCOL[s0 + s];
            float2 de = denEd[v];
            sum += __expf(leaky(esu + de.y)) * de.x;
        }
        #pragma unroll
        for (int m = 1; m < 8; m <<= 1) sum += __shfl_xor(sum, m, 8);
        float2 du = denEd[node];
        float coef = __expf(leaky(esu + du.y)) * du.x + sum;
        HF8 r; r.f4 = *(const float4*)&hhP[(size_t)node * 64 + (l8 << 3)];
        float acc[8];
        #pragma unroll
        for (int i = 0; i < 8; i++) acc[i] = coef * (float)r.h[i];
        #pragma unroll
        for (int m = 8; m <= 32; m <<= 1) {
            #pragma unroll
            for (int i = 0; i < 8; i++) acc[i] += __shfl_xor(acc[i], m, 64);
        }
        if ((l >> 3) == 0) {
            #pragma unroll
            for (int i = 0; i < 8; i++) sb[wv][(l8 << 3) + i] = acc[i];
        }
        __syncthreads();
        if (tid < 64) {
            float s = sb[0][tid] + sb[1][tid] + sb[2][tid] + sb[3][tid];
            atomicAdd(&psumP[((cb & 63) << 6) + tid], s);
        }
    }
}

// ---------------- fused classifier (reduces psumP, applies layer-2 biases) ----------------
__global__ void k_cls(const float* __restrict__ gsum, const int* __restrict__ gstart,
                      const int* __restrict__ gend, const float* __restrict__ psumP,
                      const float* __restrict__ bg, const float* __restrict__ bp,
                      const float* __restrict__ W1, const float* __restrict__ b1,
                      const float* __restrict__ w2, const float* __restrict__ b2,
                      float* __restrict__ out){
    __shared__ float W1s[128 * 64];
    __shared__ float pv[64], bgs[64];
    int tid = threadIdx.x;
    for (int k = tid; k < 128 * 64; k += 256) W1s[k] = W1[k];
    if (tid < 64) {
        float s = 0.f;
        for (int sl = 0; sl < 64; sl++) s += psumP[(sl << 6) + tid];
        pv[tid] = s * (1.0f / (float)NP) + bp[tid];
        bgs[tid] = bg[tid];
    }
    __syncthreads();
    int g = blockIdx.x * 4 + (tid >> 6);
    int j = tid & 63;
    float cntf = (float)(gend[g] - gstart[g]);
    float inv = 1.0f / fmaxf(cntf, 1.0f);
    float acc = b1[j];
    #pragma unroll 8
    for (int k = 0; k < 64; k++) acc += (gsum[g * 64 + k] * inv + bgs[k]) * W1s[k * 64 + j];
    #pragma unroll 8
    for (int k = 0; k < 64; k++) acc += pv[k] * W1s[(64 + k) * 64 + j];
    float v = fmaxf(acc, 0.f) * w2[j];
    #pragma unroll
    for (int off = 32; off > 0; off >>= 1) v += __shfl_down(v, off, 64);
    if (j == 0) out[g] = 1.0f / (1.0f + expf(-(v + b2[0])));
}

extern "C" void kernel_launch(void* const* d_in, const int* in_sizes, int n_in,
                              void* d_out, int out_size, void* d_ws, size_t ws_size,
                              hipStream_t stream) {
    const float* mol_x   = (const float*)d_in[0];
    const int*   mol_ei  = (const int*)d_in[1];
    const int*   mol_bat = (const int*)d_in[2];
    const float* prot_x  = (const float*)d_in[3];
    const int*   prot_ei = (const int*)d_in[4];
    const float* gcn_w1  = (const float*)d_in[5];
    const float* gcn_b1  = (const float*)d_in[6];
    const float* gcn_w2  = (const float*)d_in[7];
    const float* gcn_b2  = (const float*)d_in[8];
    const float* gat_w1  = (const float*)d_in[9];
    const float* gat_as1 = (const float*)d_in[10];
    const float* gat_ad1 = (const float*)d_in[11];
    const float* gat_b1  = (const float*)d_in[12];
    const float* gat_w2  = (const float*)d_in[13];
    const float* gat_as2 = (const float*)d_in[14];
    const float* gat_ad2 = (const float*)d_in[15];
    const float* gat_b2  = (const float*)d_in[16];
    const float* cls_w1  = (const float*)d_in[17];
    const float* cls_b1  = (const float*)d_in[18];
    const float* cls_w2  = (const float*)d_in[19];
    const float* cls_b2  = (const float*)d_in[20];
    float* out = (float*)d_out;

    float* ws_f = (float*)d_ws;

    // ---- persistent tail ----
    float* T       = ws_f + 16777216;
    float* gsum    = T;                       // 262,144 floats (zeroed)
    int*   gstart  = (int*)(T + 262144);      // 4,096 (zeroed)
    int*   gend    = (int*)(T + 266240);      // 4,096 (zeroed)
    int*   coarseM = (int*)(T + 270400);      // 512 (zeroed)
    int*   coarseP = (int*)(T + 270912);      // 512 (zeroed)
    int*   cstartM = (int*)(T + 271424);      // 513
    int*   cursorM = (int*)(T + 271937);      // 512
    int*   cstartP = (int*)(T + 272449);      // 513
    int*   cursorP = (int*)(T + 272962);      // 512
    float* psumP   = T + 273474;              // 64x64 (zeroed)
    int*   coarseS = (int*)(T + 277632);      // 512 (zeroed)
    int*   cstartS = (int*)(T + 278144);      // 513
    int*   cursorS = (int*)(T + 278657);      // 512  -> zeroed tail ends T+279,169
    __half* wPackC = (__half*)(T + 279200);   // 7168 halves (3584 floats)
    __half* wPackG = (__half*)(T + 282784);   // 7168 halves -> ends T+286,368

    // ---- early CSR staging (dead after k_fine2) ----
    unsigned* bufM = (unsigned*)ws_f;                    // [0, 524,288)
    unsigned* bufP = (unsigned*)(ws_f + 524352);         // [524,352, 2,124,416)
    unsigned* bufS = (unsigned*)(ws_f + 2124480);        // [2,124,480, 3,724,480)

    // ---- overlapping phase regions (offsets in floats) ----
    __half*   h2hP      = (__half*)ws_f;
    int*      srcCOL    = (int*)(ws_f + 4194304);
    float*    es2       = ws_f + 5794304;
    float*    ed2       = ws_f + 5894304;
    float*    es1       = ws_f + 7794304;
    float*    ed1       = ws_f + 7894304;
    float2*   denEd     = (float2*)(ws_f + 7994304);
    int*      srcRP     = (int*)(ws_f + 8194304);
    __half*   h2hM      = (__half*)(ws_f + 8388608);
    int*      molCOL    = (int*)(ws_f + 12582912);       // EM+64 -> 13,107,264
    int*      molRP     = (int*)(ws_f + 13107264);       // NM -> 13,238,336 (+pad)
    float*    dinvM     = ws_f + 13238352;               // NM -> 13,369,424 (+pad)
    __half*   x8h       = (__half*)(ws_f + 13369440);    // NM*8 halves -> 13,893,728 (+pad)
    int*      protCOL   = (int*)(ws_f + 14680256);       // EP+64 -> 16,280,320
    int*      protRP    = (int*)(ws_f + 16280320);       // NP -> 16,380,320
    __half*   x32h      = (__half*)(ws_f + 17100000);    // NP*32 halves -> 18,700,000

    // single upfront zero of gsum..cursorS (contiguous tail region)
    (void)hipMemsetAsync(gsum, 0, (size_t)279169 * sizeof(float), stream);

    // ================= merged CSR build (mol-dst + prot-dst + prot-src) =================
    k_hist2<<<256 + 391 + 391, 256, 0, stream>>>(mol_ei + EM, prot_ei + EP, prot_ei,
                                                 coarseM, coarseP, coarseS);
    // scan + one-time packed weight transposes (blocks 3,4)
    k_scan2<<<5, 512, 0, stream>>>(coarseM, cstartM, cursorM, coarseP, cstartP, cursorP,
                                   coarseS, cstartS, cursorS,
                                   gcn_w1, gcn_w2, gat_w1, gat_w2, wPackC, wPackG);
    k_part2<<<128 + 391 + 391, 256, 0, stream>>>(mol_ei, cursorM, bufM, prot_ei, cursorP, bufP,
                                                 cursorS, bufS);
    // fine pass + fused prep epilogue
    k_fine2<<<512 + 391 + 391, 256, 0, stream>>>(bufM, cstartM, molRP, molCOL, dinvM,
                                                 bufP, cstartP, protRP, protCOL,
                                                 bufS, cstartS, srcRP, srcCOL,
                                                 mol_x, x8h, mol_bat, gstart, gend,
                                                 prot_x, gat_w1, gat_as1, gat_ad1,
                                                 x32h, es1, ed1);

    // ================= fused L1 gather + MLP (prot-first LPT order) =================
    k_l1m<<<PROTB + NM/64, 256, 0, stream>>>(molRP, molCOL, x8h, dinvM,
                                             wPackC, gcn_b1, h2hM,
                                             protRP, protCOL, x32h, es1, ed1,
                                             wPackG, gat_b1, gat_as2, gat_ad2,
                                             h2hP, es2, ed2);

    // ================= L2 phase: prot den -> (mol gather+pool || prot coef*row sum) =========
    k_den<<<NP/16, 256, 0, stream>>>(protRP, protCOL, es2, ed2, denEd);
    k_l2c<<<NM/16 + NP/32, 256, 0, stream>>>(molRP, molCOL, h2hM, dinvM, mol_bat, gsum,
                                             srcRP, srcCOL, es2, denEd, h2hP, psumP);

    // ================= classifier (reduces psumP, applies layer-2 biases) =================
    k_cls<<<NG/4, 256, 0, stream>>>(gsum, gstart, gend, psumP, gcn_b2, gat_b2,
                                    cls_w1, cls_b1, cls_w2, cls_b2, out);
}

// Round 13
// 265.345 us; speedup vs baseline: 1.0865x; 1.0613x over previous
//
#include <hip/hip_runtime.h>
#include <hip/hip_fp16.h>

#define NM 131072   // mol nodes
#define EM 524288   // mol edges
#define NG 4096     // graphs
#define DM 6        // mol in dim
#define NP 100000   // prot nodes
#define EP 1600000  // prot edges
#define DP 20       // prot in dim

#define MSTR 1536   // mol bucket stride (exp 1024, +50%)
#define PSTR 5120   // prot bucket stride (exp 4096, +25%)

static inline int cdiv(int a, int b){ return (a + b - 1) / b; }

__device__ __forceinline__ float leaky(float x){ return x > 0.f ? x : 0.2f * x; }

union H8 { float4 f4; __half2 h2[4]; };
union HF8 { float4 f4; _Float16 h[8]; };

typedef _Float16 f16x8 __attribute__((ext_vector_type(8)));
typedef float    f32x4 __attribute__((ext_vector_type(4)));

// ================= single-pass bucketed partition (fixed-stride buckets, no hist/scan) ======
// blocks 0-127: mol-dst | 128-518: prot-dst | 519-909: prot-src | 910/911: weight packing
__global__ void k_part2(const int* __restrict__ eiM, int* __restrict__ cursorM, unsigned* __restrict__ bufM,
                        const int* __restrict__ eiP, int* __restrict__ cursorP, unsigned* __restrict__ bufP,
                        int* __restrict__ cursorS, unsigned* __restrict__ bufS,
                        const float* __restrict__ gcn_w1, const float* __restrict__ gcn_w2,
                        const float* __restrict__ gat_w1, const float* __restrict__ gat_w2,
                        __half* __restrict__ wPackC, __half* __restrict__ wPackG){
    int t = threadIdx.x;
    if (blockIdx.x >= 910) {
        // one-time f16 weight packing in EXACT k_l1m LDS layout: [W2T 64x72 | W1T 64x40]
        const float* W1 = (blockIdx.x == 910) ? gcn_w1 : gat_w1;
        const float* W2 = (blockIdx.x == 910) ? gcn_w2 : gat_w2;
        __half* wp = (blockIdx.x == 910) ? wPackC : wPackG;
        int D = (blockIdx.x == 910) ? DM : DP;
        for (int i = t; i < 4608; i += 256) {
            int colj = i / 72, k = i - colj * 72;
            wp[i] = __float2half(k < 64 ? W2[k * 64 + colj] : 0.f);
        }
        for (int i = t; i < 2560; i += 256) {
            int colj = i / 40, k = i - colj * 40;
            wp[4608 + i] = __float2half(k < D ? W1[k * 64 + colj] : 0.f);
        }
        return;
    }
    __shared__ int lh[512];
    __shared__ int lbase[512];
    const int* ei; int* cursor; unsigned* buf; int E, K, base, sw, STR;
    if (blockIdx.x < 128)      { ei = eiM; cursor = cursorM; buf = bufM; E = EM; K = 512; base = blockIdx.x * 4096; sw = 0; STR = MSTR; }
    else if (blockIdx.x < 519) { ei = eiP; cursor = cursorP; buf = bufP; E = EP; K = 391; base = (blockIdx.x - 128) * 4096; sw = 0; STR = PSTR; }
    else                       { ei = eiP; cursor = cursorS; buf = bufS; E = EP; K = 391; base = (blockIdx.x - 519) * 4096; sw = 1; STR = PSTR; }
    for (int i = t; i < K; i += 256) lh[i] = 0;
    __syncthreads();
    int end = min(base + 4096, E);
    unsigned pay[16]; int bslot[16];
    int cnt = 0;
    for (int e = base + t; e < end; e += 256) {
        int u = ei[e], v = ei[E + e];
        int key = sw ? u : v, oth = sw ? v : u;
        int b = key >> 8;
        int ls = atomicAdd(&lh[b], 1);
        pay[cnt] = ((unsigned)(key & 255) << 24) | (unsigned)oth;
        bslot[cnt] = (b << 13) | ls;
        cnt++;
    }
    __syncthreads();
    for (int i = t; i < K; i += 256)
        lbase[i] = lh[i] ? atomicAdd(&cursor[i], lh[i]) : 0;
    __syncthreads();
    for (int j = 0; j < cnt; j++) {
        int b = bslot[j] >> 13, ls = bslot[j] & 8191;
        int pos = lbase[b] + ls;
        if (pos < STR)                          // overflow guard (16-sigma margin, never hit)
            buf[(size_t)b * STR + pos] = pay[j];
    }
}

// fine pass (fixed-stride buckets) + fused prep epilogue
__global__ void k_fine2(const unsigned* __restrict__ bufM, const int* __restrict__ cntM,
                        int* __restrict__ molRP, int* __restrict__ molCOL, float* __restrict__ dinv,
                        const unsigned* __restrict__ bufP, const int* __restrict__ cntP,
                        int* __restrict__ protRP, int* __restrict__ protCOL,
                        const unsigned* __restrict__ bufS, const int* __restrict__ cntS,
                        int* __restrict__ srcRP, int* __restrict__ srcCOL,
                        const float* __restrict__ mol_x, __half* __restrict__ x8,
                        const int* __restrict__ batch, int* __restrict__ gstart,
                        int* __restrict__ gend,
                        const float* __restrict__ prot_x, const float* __restrict__ W1a,
                        const float* __restrict__ as_, const float* __restrict__ ad_,
                        __half* __restrict__ x32, float* __restrict__ es,
                        float* __restrict__ ed_){
    __shared__ float vas[20], vds[20];
    int t = threadIdx.x;
    int k; const unsigned* buf; const int* cntA; int* rp; int* col; int n, OB, dv, pp, STR;
    if (blockIdx.x < 512)      { k = blockIdx.x;       buf = bufM; cntA = cntM; rp = molRP;  col = molCOL;  n = NM; OB = 20; dv = 1; pp = 0; STR = MSTR; }
    else if (blockIdx.x < 903) { k = blockIdx.x - 512; buf = bufP; cntA = cntP; rp = protRP; col = protCOL; n = NP; OB = 21; dv = 0; pp = 1; STR = PSTR; }
    else                       { k = blockIdx.x - 903; buf = bufS; cntA = cntS; rp = srcRP;  col = srcCOL;  n = NP; OB = 21; dv = 0; pp = 0; STR = PSTR; }
    if (pp) {
        if (t < 20) {
            float s = 0.f;
            for (int j = 0; j < 64; j++) s += W1a[t * 64 + j] * as_[j];
            vas[t] = s;
        } else if (t >= 32 && t < 52) {
            int kk = t - 32;
            float s = 0.f;
            for (int j = 0; j < 64; j++) s += W1a[kk * 64 + j] * ad_[j];
            vds[kk] = s;
        }
    }
    int start = k * STR;
    int end = start + min(cntA[k], STR);
    __shared__ int cnt[256];
    __shared__ int cur[256];
    cnt[t] = 0;
    __syncthreads();
    for (int p = start + t; p < end; p += 256)
        atomicAdd(&cnt[buf[p] >> 24], 1);
    __syncthreads();
    int v0 = cnt[t];
    int lane = t & 63, wid = t >> 6;
    int v = v0;
    #pragma unroll
    for (int off = 1; off < 64; off <<= 1) {
        int x = __shfl_up(v, off, 64);
        if (lane >= off) v += x;
    }
    __shared__ int ws[4];
    if (lane == 63) ws[wid] = v;
    __syncthreads();
    int add = 0;
    for (int w = 0; w < wid; w++) add += ws[w];
    int excl = v + add - v0;
    int ofs = start + excl;
    cur[t] = ofs;
    int idx = (k << 8) + t;
    if (idx < n) {
        rp[idx] = (int)((unsigned)ofs | ((unsigned)v0 << OB));
        if (dv) dinv[idx] = rsqrtf((float)(v0 + 1));
    }
    __syncthreads();
    for (int p = start + t; p < end; p += 256) {
        unsigned pk = buf[p];
        int slot = atomicAdd(&cur[pk >> 24], 1);
        col[slot] = (int)(pk & 0xFFFFFFu);
    }
    // ---- fused prep epilogue ----
    if (dv) {
        float dd = rsqrtf((float)(v0 + 1));
        H8 r;
        #pragma unroll
        for (int kk = 0; kk < 3; kk++)
            r.h2[kk] = __floats2half2_rn(dd * mol_x[idx*6 + 2*kk], dd * mol_x[idx*6 + 2*kk + 1]);
        r.h2[3] = __floats2half2_rn(0.f, 0.f);
        *(float4*)&x8[(size_t)idx * 8] = r.f4;
        int g = batch[idx];
        if (idx == 0 || batch[idx - 1] != g) gstart[g] = idx;
        if (idx == NM - 1 || batch[idx + 1] != g) gend[g] = idx + 1;
    } else if (pp && idx < n) {
        float xv[20];
        float s = 0.f, d = 0.f;
        #pragma unroll
        for (int kk = 0; kk < 20; kk++) {
            xv[kk] = prot_x[idx*20 + kk];
            s += xv[kk] * vas[kk]; d += xv[kk] * vds[kk];
        }
        es[idx] = s; ed_[idx] = d;
        H8 r0, r1, r2, rz;
        #pragma unroll
        for (int kk = 0; kk < 4; kk++) r0.h2[kk] = __floats2half2_rn(xv[2*kk],   xv[2*kk+1]);
        #pragma unroll
        for (int kk = 0; kk < 4; kk++) r1.h2[kk] = __floats2half2_rn(xv[8+2*kk], xv[9+2*kk]);
        r2.h2[0] = __floats2half2_rn(xv[16], xv[17]);
        r2.h2[1] = __floats2half2_rn(xv[18], xv[19]);
        r2.h2[2] = __floats2half2_rn(0.f, 0.f);
        r2.h2[3] = __floats2half2_rn(0.f, 0.f);
        rz.h2[0] = rz.h2[1] = rz.h2[2] = rz.h2[3] = __floats2half2_rn(0.f, 0.f);
        *(float4*)&x32[(size_t)idx * 32]      = r0.f4;
        *(float4*)&x32[(size_t)idx * 32 + 8]  = r1.f4;
        *(float4*)&x32[(size_t)idx * 32 + 16] = r2.f4;
        *(float4*)&x32[(size_t)idx * 32 + 24] = rz.f4;
    }
}

// ================= fused L1 gather + MLP (MFMA f16 16x16x32), 64 nodes/block, 4 waves =====
// LDS overlay (halves): W2T [64][72] @0, W1T [64][40] @4608, Ain [4][16][40] @7168,
//                       X1 [4][16][72] @4608 (overlays W1T+Ain after both are dead).
// 19456 B -> 8 blocks/CU. Weights staged by float4 copy from pre-packed global blob.
template<int D, int ATT, int SCALE>
__device__ __forceinline__ void l1m_body(__half* smemh, int bid, int tid,
                                         const int* __restrict__ rp, const int* __restrict__ col,
                                         const __half* __restrict__ xrow,
                                         const float* __restrict__ es1, const float* __restrict__ ed1,
                                         const __half* __restrict__ wPack, const float* __restrict__ b1,
                                         const float* __restrict__ as_, const float* __restrict__ ad_,
                                         __half* __restrict__ hout, float* __restrict__ esO,
                                         float* __restrict__ edO, const float* __restrict__ dinv,
                                         int n){
    __half* W2Ts = smemh;            // 4608 halves @0
    __half* W1Ts = smemh + 4608;     // 2560 halves @4608
    __half* AinS = smemh + 7168;     // 2560 halves @7168 (4 waves * 640)
    __half* X1S  = smemh + 4608;     // 4608 halves overlay @4608
    int lane = tid & 63, w = tid >> 6;
    int c = lane & 15, g = lane >> 4;
    int node0 = bid * 64 + w * 16;

    // ---- stage packed weights: 7168 halves = 896 float4, coalesced, conflict-free ----
    {
        const float4* wp4 = (const float4*)wPack;
        float4* sm4 = (float4*)smemh;
        #pragma unroll
        for (int i = 0; i < 3; i++) sm4[tid + 256 * i] = wp4[tid + 256 * i];
        if (tid < 128) sm4[768 + tid] = wp4[768 + tid];
    }
    // ---- zero own wave's AinS slab ----
    {
        float4 z4 = make_float4(0.f, 0.f, 0.f, 0.f);
        float4* az = (float4*)(AinS + w * 640);
        for (int i = lane; i < 80; i += 64) az[i] = z4;
    }

    // ---- L1 gather straight into AinS ----
    if (!ATT) {
        // mol GCN: 16 nodes/wave, 4 lanes/node (edge slots)
        int nd = lane >> 2, q = lane & 3;
        int node = node0 + nd;
        unsigned pk = (unsigned)rp[node];
        int s0 = (int)(pk & 0xFFFFFu);
        int deg = (int)(pk >> 20);
        float acc[6] = {0.f,0.f,0.f,0.f,0.f,0.f};
        if (q == 0) {
            HF8 r; r.f4 = *(const float4*)&xrow[(size_t)node * 8];
            #pragma unroll
            for (int i = 0; i < 6; i++) acc[i] = (float)r.h[i];
        }
        for (int base = 0; base < deg; base += 4) {
            int s = base + q;
            if (s < deg) {
                int cc = col[s0 + s];
                HF8 r; r.f4 = *(const float4*)&xrow[(size_t)cc * 8];
                #pragma unroll
                for (int i = 0; i < 6; i++) acc[i] += (float)r.h[i];
            }
        }
        #pragma unroll
        for (int m = 1; m < 4; m <<= 1) {
            #pragma unroll
            for (int i = 0; i < 6; i++) acc[i] += __shfl_xor(acc[i], m, 64);
        }
        if (q == 0) {
            float dd = dinv[node];
            #pragma unroll
            for (int k = 0; k < 6; k++)
                AinS[w * 640 + nd * 40 + k] = __float2half(dd * acc[k]);
        }
    } else {
        // prot GAT: 4 rounds of {4 nodes x (4 slots x 4 chunks)}; chunk 3 dead (zero-pad).
        int nd4 = lane >> 4;
        int slot = (lane >> 2) & 3;
        int chunk = lane & 3;
        bool live = chunk < 3;
        for (int rr = 0; rr < 4; rr++) {
            int row = rr * 4 + nd4;
            int node = node0 + row;
            bool valid = node < n;
            int nodeC = valid ? node : 0;
            unsigned pk = (unsigned)rp[nodeC];
            int s0 = (int)(pk & 0x1FFFFFu);
            int deg = valid ? (int)(pk >> 21) : 0;
            float edv = ed1[nodeC];
            float selfw = __expf(leaky(es1[nodeC] + edv));
            float acc[8] = {0.f,0.f,0.f,0.f,0.f,0.f,0.f,0.f};
            float den = (slot == 0) ? selfw : 0.f;
            if (slot == 0 && valid && live) {
                HF8 r; r.f4 = *(const float4*)&xrow[(size_t)node * 32 + (chunk << 3)];
                #pragma unroll
                for (int i = 0; i < 8; i++) acc[i] = selfw * (float)r.h[i];
            }
            for (int base = 0; base < deg; base += 4) {
                int s = base + slot;
                if (s < deg) {
                    int u = col[s0 + s];
                    float ww = __expf(leaky(es1[u] + edv));
                    if (live) {
                        HF8 r; r.f4 = *(const float4*)&xrow[(size_t)u * 32 + (chunk << 3)];
                        #pragma unroll
                        for (int i = 0; i < 8; i++) acc[i] += ww * (float)r.h[i];
                    }
                    den += ww;
                }
            }
            #pragma unroll
            for (int m = 4; m <= 8; m <<= 1) {
                #pragma unroll
                for (int i = 0; i < 8; i++) acc[i] += __shfl_xor(acc[i], m, 64);
                den += __shfl_xor(den, m, 64);
            }
            float inv = 1.f / den;
            if (slot == 0 && valid && live) {
                #pragma unroll
                for (int i = 0; i < 8; i++) {
                    int k = (chunk << 3) + i;
                    if (k < 20) AinS[w * 640 + row * 40 + k] = __float2half(acc[i] * inv);
                }
            }
        }
    }
    __syncthreads();   // gather + weight staging complete

    // ---- layer 1: register-cache A and all W1T fragments, then sync, then MFMA+X1 write ----
    f32x4 zz = {0.f, 0.f, 0.f, 0.f};
    f16x8 a1 = *(const f16x8*)&AinS[w * 640 + c * 40 + 8 * g];
    f16x8 b1f[4];
    #pragma unroll
    for (int t = 0; t < 4; t++)
        b1f[t] = *(const f16x8*)&W1Ts[(16 * t + c) * 40 + 8 * g];
    __syncthreads();   // all W1Ts/AinS reads done -> X1S overlay may be written
    #pragma unroll
    for (int t = 0; t < 4; t++) {
        f32x4 h = __builtin_amdgcn_mfma_f32_16x16x32_f16(a1, b1f[t], zz, 0, 0, 0);
        float bv = b1[16 * t + c];
        #pragma unroll
        for (int r = 0; r < 4; r++) {
            float v = fmaxf(h[r] + bv, 0.f);
            X1S[w * 1152 + (4 * g + r) * 72 + 16 * t + c] = __float2half(v);
        }
    }
    // X1S slabs are wave-local: no block sync needed before layer 2

    // ---- layer 2 ----
    f32x4 acc2[4];
    #pragma unroll
    for (int t = 0; t < 4; t++) acc2[t] = zz;
    #pragma unroll
    for (int kt = 0; kt < 2; kt++) {
        f16x8 a = *(const f16x8*)&X1S[w * 1152 + c * 72 + 32 * kt + 8 * g];
        #pragma unroll
        for (int t = 0; t < 4; t++) {
            f16x8 b = *(const f16x8*)&W2Ts[(16 * t + c) * 72 + 32 * kt + 8 * g];
            acc2[t] = __builtin_amdgcn_mfma_f32_16x16x32_f16(a, b, acc2[t], 0, 0, 0);
        }
    }

    if (ATT) {
        float asv[4], adv[4];
        #pragma unroll
        for (int t = 0; t < 4; t++) { asv[t] = as_[16 * t + c]; adv[t] = ad_[16 * t + c]; }
        #pragma unroll
        for (int r = 0; r < 4; r++) {
            float xa = 0.f, ya = 0.f;
            #pragma unroll
            for (int t = 0; t < 4; t++) { xa += acc2[t][r] * asv[t]; ya += acc2[t][r] * adv[t]; }
            #pragma unroll
            for (int m = 1; m < 16; m <<= 1) { xa += __shfl_xor(xa, m, 16); ya += __shfl_xor(ya, m, 16); }
            int nd = node0 + 4 * g + r;
            if (c == 0 && nd < n) { esO[nd] = xa; edO[nd] = ya; }
        }
    }
    if (SCALE) {
        #pragma unroll
        for (int r = 0; r < 4; r++) {
            float dd = dinv[node0 + 4 * g + r];
            #pragma unroll
            for (int t = 0; t < 4; t++) acc2[t][r] *= dd;
        }
    }

    // ---- repack through X1S (wave-local) -> coalesced float4 f16 stores ----
    #pragma unroll
    for (int t = 0; t < 4; t++) {
        #pragma unroll
        for (int r = 0; r < 4; r++)
            X1S[w * 1152 + (4 * g + r) * 72 + 16 * t + c] = __float2half(acc2[t][r]);
    }
    int rr2 = lane >> 2, seg = lane & 3;
    union { f16x8 h; float4 f; } o;
    o.h = *(const f16x8*)&X1S[w * 1152 + rr2 * 72 + seg * 16];
    int nd = node0 + rr2;
    if (!ATT || nd < n)
        *(float4*)&hout[(size_t)nd * 64 + seg * 16] = o.f;
}

#define PROTB 1563   // cdiv(NP, 64)

__global__ __launch_bounds__(256, 8)
void k_l1m(const int* __restrict__ molRP, const int* __restrict__ molCOL,
           const __half* __restrict__ x8, const float* __restrict__ dinvM,
           const __half* __restrict__ wPackC, const float* __restrict__ gcn_b1,
           __half* __restrict__ h2hM,
           const int* __restrict__ protRP, const int* __restrict__ protCOL,
           const __half* __restrict__ x32, const float* __restrict__ es1,
           const float* __restrict__ ed1,
           const __half* __restrict__ wPackG, const float* __restrict__ gat_b1,
           const float* __restrict__ as2, const float* __restrict__ ad2,
           __half* __restrict__ h2hP, float* __restrict__ es2, float* __restrict__ ed2){
    __shared__ __attribute__((aligned(16))) __half smemh[9728];   // 19456 B -> 8 blocks/CU
    if (blockIdx.x < PROTB)   // long prot blocks first (LPT)
        l1m_body<20, 1, 0>(smemh, blockIdx.x, threadIdx.x, protRP, protCOL, x32, es1, ed1,
                           wPackG, gat_b1, as2, ad2,
                           h2hP, es2, ed2, nullptr, NP);
    else
        l1m_body<6, 0, 1>(smemh, blockIdx.x - PROTB, threadIdx.x, molRP, molCOL, x8, nullptr, nullptr,
                          wPackC, gcn_b1, nullptr, nullptr,
                          h2hM, nullptr, nullptr, dinvM, NM);
}

// ================= prot den (dst-CSR, es2-only gather) =================
__global__ void k_den(const int* __restrict__ protRP, const int* __restrict__ protCOL,
                      const float* __restrict__ es, const float* __restrict__ ed_,
                      float2* __restrict__ denEd){
    int tid = threadIdx.x;
    int node = (blockIdx.x << 4) + (tid >> 4);
    int l16 = tid & 15;
    unsigned pk = (unsigned)protRP[node];
    int s0 = (int)(pk & 0x1FFFFFu);
    int deg = (int)(pk >> 21);
    float edv = ed_[node];
    float den = 0.f;
    for (int s = l16; s < deg; s += 16) {
        int u = protCOL[s0 + s];
        den += __expf(leaky(es[u] + edv));
    }
    #pragma unroll
    for (int m = 1; m < 16; m <<= 1) den += __shfl_xor(den, m, 16);
    if (l16 == 0) {
        float selfw = __expf(leaky(es[node] + edv));
        denEd[node] = make_float2(1.f / (den + selfw), edv);
    }
}

// ================= merged L2: mol gather+pool (8192 blocks) + prot coef*row sum (3125 blocks) ==
__global__ void k_l2c(const int* __restrict__ molRP, const int* __restrict__ molCOL,
                      const __half* __restrict__ hhM, const float* __restrict__ dinv,
                      const int* __restrict__ batch, float* __restrict__ gsum,
                      const int* __restrict__ srcRP, const int* __restrict__ srcCOL,
                      const float* __restrict__ es, const float2* __restrict__ denEd,
                      const __half* __restrict__ hhP, float* __restrict__ psumP){
    __shared__ float sb[16][64];
    __shared__ int gidS[16];
    int tid = threadIdx.x;
    if (blockIdx.x < NM/16) {
        // mol L2: 16 nodes/block, 4 nodes/wave; per node: 2 edge-slots x 8 feature-chunks
        int bid = blockIdx.x;
        int wv = tid >> 6, l = tid & 63;
        int nd = l >> 4;
        int slot = (l >> 3) & 1;
        int q = l & 7;
        int node = (bid << 4) + (wv << 2) + nd;
        int row = (wv << 2) + nd;
        unsigned pk = (unsigned)molRP[node];
        int s0 = (int)(pk & 0xFFFFFu);
        int deg = (int)(pk >> 20);
        float acc[8] = {0.f,0.f,0.f,0.f,0.f,0.f,0.f,0.f};
        if (slot == 0) {
            HF8 r; r.f4 = *(const float4*)&hhM[(size_t)node * 64 + (q << 3)];
            #pragma unroll
            for (int i = 0; i < 8; i++) acc[i] = (float)r.h[i];
        }
        for (int base = 0; base < deg; base += 2) {
            int s = base + slot;
            if (s < deg) {
                int u = molCOL[s0 + s];
                HF8 r; r.f4 = *(const float4*)&hhM[(size_t)u * 64 + (q << 3)];
                #pragma unroll
                for (int i = 0; i < 8; i++) acc[i] += (float)r.h[i];
            }
        }
        #pragma unroll
        for (int i = 0; i < 8; i++) acc[i] += __shfl_xor(acc[i], 8, 64);
        if (slot == 0) {
            float sc = dinv[node];
            #pragma unroll
            for (int i = 0; i < 8; i++) sb[row][(q << 3) + i] = acc[i] * sc;
        }
        if (l == (nd << 4)) gidS[row] = batch[node];
        __syncthreads();
        if (tid < 64) {
            int i = 0;
            while (i < 16) {
                int g0 = gidS[i];
                float s = sb[i][tid];
                int j = i + 1;
                while (j < 16 && gidS[j] == g0) { s += sb[j][tid]; j++; }
                atomicAdd(&gsum[(g0 << 6) + tid], s);
                i = j;
            }
        }
    } else {
        // prot: per-source coef gather + coalesced weighted row accumulate
        int cb = blockIdx.x - NM/16;
        int wv = tid >> 6, l = tid & 63;
        int node = cb * 32 + (tid >> 3);
        int l8 = tid & 7;
        unsigned pk = (unsigned)srcRP[node];
        int s0 = (int)(pk & 0x1FFFFFu);
        int deg = (int)(pk >> 21);
        float esu = es[node];
        float sum = 0.f;
        for (int s = l8; s < deg; s += 8) {
            int v = srcCOL[s0 + s];
            float2 de = denEd[v];
            sum += __expf(leaky(esu + de.y)) * de.x;
        }
        #pragma unroll
        for (int m = 1; m < 8; m <<= 1) sum += __shfl_xor(sum, m, 8);
        float2 du = denEd[node];
        float coef = __expf(leaky(esu + du.y)) * du.x + sum;
        HF8 r; r.f4 = *(const float4*)&hhP[(size_t)node * 64 + (l8 << 3)];
        float acc[8];
        #pragma unroll
        for (int i = 0; i < 8; i++) acc[i] = coef * (float)r.h[i];
        #pragma unroll
        for (int m = 8; m <= 32; m <<= 1) {
            #pragma unroll
            for (int i = 0; i < 8; i++) acc[i] += __shfl_xor(acc[i], m, 64);
        }
        if ((l >> 3) == 0) {
            #pragma unroll
            for (int i = 0; i < 8; i++) sb[wv][(l8 << 3) + i] = acc[i];
        }
        __syncthreads();
        if (tid < 64) {
            float s = sb[0][tid] + sb[1][tid] + sb[2][tid] + sb[3][tid];
            atomicAdd(&psumP[((cb & 63) << 6) + tid], s);
        }
    }
}

// ---------------- fused classifier (reduces psumP, applies layer-2 biases) ----------------
__global__ void k_cls(const float* __restrict__ gsum, const int* __restrict__ gstart,
                      const int* __restrict__ gend, const float* __restrict__ psumP,
                      const float* __restrict__ bg, const float* __restrict__ bp,
                      const float* __restrict__ W1, const float* __restrict__ b1,
                      const float* __restrict__ w2, const float* __restrict__ b2,
                      float* __restrict__ out){
    __shared__ float W1s[128 * 64];
    __shared__ float pv[64], bgs[64];
    int tid = threadIdx.x;
    for (int k = tid; k < 128 * 64; k += 256) W1s[k] = W1[k];
    if (tid < 64) {
        float s = 0.f;
        for (int sl = 0; sl < 64; sl++) s += psumP[(sl << 6) + tid];
        pv[tid] = s * (1.0f / (float)NP) + bp[tid];
        bgs[tid] = bg[tid];
    }
    __syncthreads();
    int g = blockIdx.x * 4 + (tid >> 6);
    int j = tid & 63;
    float cntf = (float)(gend[g] - gstart[g]);
    float inv = 1.0f / fmaxf(cntf, 1.0f);
    float acc = b1[j];
    #pragma unroll 8
    for (int k = 0; k < 64; k++) acc += (gsum[g * 64 + k] * inv + bgs[k]) * W1s[k * 64 + j];
    #pragma unroll 8
    for (int k = 0; k < 64; k++) acc += pv[k] * W1s[(64 + k) * 64 + j];
    float v = fmaxf(acc, 0.f) * w2[j];
    #pragma unroll
    for (int off = 32; off > 0; off >>= 1) v += __shfl_down(v, off, 64);
    if (j == 0) out[g] = 1.0f / (1.0f + expf(-(v + b2[0])));
}

extern "C" void kernel_launch(void* const* d_in, const int* in_sizes, int n_in,
                              void* d_out, int out_size, void* d_ws, size_t ws_size,
                              hipStream_t stream) {
    const float* mol_x   = (const float*)d_in[0];
    const int*   mol_ei  = (const int*)d_in[1];
    const int*   mol_bat = (const int*)d_in[2];
    const float* prot_x  = (const float*)d_in[3];
    const int*   prot_ei = (const int*)d_in[4];
    const float* gcn_w1  = (const float*)d_in[5];
    const float* gcn_b1  = (const float*)d_in[6];
    const float* gcn_w2  = (const float*)d_in[7];
    const float* gcn_b2  = (const float*)d_in[8];
    const float* gat_w1  = (const float*)d_in[9];
    const float* gat_as1 = (const float*)d_in[10];
    const float* gat_ad1 = (const float*)d_in[11];
    const float* gat_b1  = (const float*)d_in[12];
    const float* gat_w2  = (const float*)d_in[13];
    const float* gat_as2 = (const float*)d_in[14];
    const float* gat_ad2 = (const float*)d_in[15];
    const float* gat_b2  = (const float*)d_in[16];
    const float* cls_w1  = (const float*)d_in[17];
    const float* cls_b1  = (const float*)d_in[18];
    const float* cls_w2  = (const float*)d_in[19];
    const float* cls_b2  = (const float*)d_in[20];
    float* out = (float*)d_out;

    float* ws_f = (float*)d_ws;

    // ---- persistent tail ----
    float* T       = ws_f + 16777216;
    float* gsum    = T;                       // 262,144 floats (zeroed)
    int*   gstart  = (int*)(T + 262144);      // 4,096 (zeroed)
    int*   gend    = (int*)(T + 266240);      // 4,096 (zeroed)
    int*   cursorM = (int*)(T + 270400);      // 512 (zeroed; bucket counters)
    int*   cursorP = (int*)(T + 270912);      // 512 (zeroed)
    int*   cursorS = (int*)(T + 271424);      // 512 (zeroed)
    float* psumP   = T + 273474;              // 64x64 (zeroed)
    __half* wPackC = (__half*)(T + 279200);   // 7168 halves
    __half* wPackG = (__half*)(T + 282784);   // 7168 halves -> ends T+286,368

    // ---- fixed-stride bucket staging (dead after k_fine2) ----
    unsigned* bufM = (unsigned*)ws_f;                    // 512*1536  = [0, 786,432)
    unsigned* bufP = (unsigned*)(ws_f + 786432);         // 391*5120  = [786,432, 2,788,352)
    unsigned* bufS = (unsigned*)(ws_f + 2788352);        // 391*5120  = [2,788,352, 4,790,272)

    // ---- overlapping phase regions (offsets in floats) ----
    // h2hP [0,3.2M) written at l1m (bufs dead). srcCOL/es/ed etc. placed clear of bufs
    // because k_fine2 writes them while reading the bufs.
    __half*   h2hP      = (__half*)ws_f;
    int*      srcCOL    = (int*)(ws_f + 4790400);        // 391*5120 -> ends 6,792,320
    float*    es2       = ws_f + 6792320;
    float*    ed2       = ws_f + 6892320;
    float2*   denEd     = (float2*)(ws_f + 6992320);     // 2*NP -> ends 7,192,320
    int*      srcRP     = (int*)(ws_f + 7192320);        // NP -> 7,292,320
    float*    es1       = ws_f + 7292352;                // NP -> 7,392,352
    float*    ed1       = ws_f + 7392384;                // NP -> 7,492,384
    __half*   h2hM      = (__half*)(ws_f + 8388608);     // NM*64 halves -> 12,582,912
    int*      molCOL    = (int*)(ws_f + 12582912);       // 512*1536 -> 13,369,344 (+pad)
    int*      molRP     = (int*)(ws_f + 13369408);       // NM -> 13,500,480
    float*    dinvM     = ws_f + 13500480;               // NM -> 13,631,552
    __half*   x8h       = (__half*)(ws_f + 13631552);    // NM*8 halves -> 14,155,840
    int*      protCOL   = (int*)(ws_f + 14155840);       // 391*5120 -> 16,157,760
    int*      protRP    = (int*)(ws_f + 16157760);       // NP -> 16,257,760 (< T=16,777,216)
    __half*   x32h      = (__half*)(ws_f + 17100000);    // NP*32 halves -> 18,700,000

    // single upfront zero of gsum..psumP+cursors (contiguous tail region)
    (void)hipMemsetAsync(gsum, 0, (size_t)279169 * sizeof(float), stream);

    // ================= single-pass bucketed partition (+ weight packing blocks) ==========
    k_part2<<<912, 256, 0, stream>>>(mol_ei, cursorM, bufM, prot_ei, cursorP, bufP,
                                     cursorS, bufS,
                                     gcn_w1, gcn_w2, gat_w1, gat_w2, wPackC, wPackG);
    // fine pass + fused prep epilogue
    k_fine2<<<512 + 391 + 391, 256, 0, stream>>>(bufM, cursorM, molRP, molCOL, dinvM,
                                                 bufP, cursorP, protRP, protCOL,
                                                 bufS, cursorS, srcRP, srcCOL,
                                                 mol_x, x8h, mol_bat, gstart, gend,
                                                 prot_x, gat_w1, gat_as1, gat_ad1,
                                                 x32h, es1, ed1);

    // ================= fused L1 gather + MLP (prot-first LPT order) =================
    k_l1m<<<PROTB + NM/64, 256, 0, stream>>>(molRP, molCOL, x8h, dinvM,
                                             wPackC, gcn_b1, h2hM,
                                             protRP, protCOL, x32h, es1, ed1,
                                             wPackG, gat_b1, gat_as2, gat_ad2,
                                             h2hP, es2, ed2);

    // ================= L2 phase: prot den -> (mol gather+pool || prot coef*row sum) =========
    k_den<<<NP/16, 256, 0, stream>>>(protRP, protCOL, es2, ed2, denEd);
    k_l2c<<<NM/16 + NP/32, 256, 0, stream>>>(molRP, molCOL, h2hM, dinvM, mol_bat, gsum,
                                             srcRP, srcCOL, es2, denEd, h2hP, psumP);

    // ================= classifier (reduces psumP, applies layer-2 biases) =================
    k_cls<<<NG/4, 256, 0, stream>>>(gsum, gstart, gend, psumP, gcn_b2, gat_b2,
                                    cls_w1, cls_b1, cls_w2, cls_b2, out);
}

// Round 14
// 252.393 us; speedup vs baseline: 1.1423x; 1.0513x over previous
//
#include <hip/hip_runtime.h>
#include <hip/hip_fp16.h>

#define NM 131072   // mol nodes
#define EM 524288   // mol edges
#define NG 4096     // graphs
#define DM 6        // mol in dim
#define NP 100000   // prot nodes
#define EP 1600000  // prot edges
#define DP 20       // prot in dim

#define MSTR 1536   // mol bucket stride (exp 1024, +50%)
#define PSTR 5120   // prot bucket stride (exp 4096, +25%)

static inline int cdiv(int a, int b){ return (a + b - 1) / b; }

__device__ __forceinline__ float leaky(float x){ return x > 0.f ? x : 0.2f * x; }

union H8 { float4 f4; __half2 h2[4]; };
union HF8 { float4 f4; _Float16 h[8]; };

typedef _Float16 f16x8 __attribute__((ext_vector_type(8)));
typedef float    f32x4 __attribute__((ext_vector_type(4)));

// ================= single-pass bucketed partition (fixed-stride buckets, no hist/scan) ======
// blocks 0-127: mol-dst | 128-518: prot-dst | 519-909: prot-src | 910/911: weight packing
__global__ void k_part2(const int* __restrict__ eiM, int* __restrict__ cursorM, unsigned* __restrict__ bufM,
                        const int* __restrict__ eiP, int* __restrict__ cursorP, unsigned* __restrict__ bufP,
                        int* __restrict__ cursorS, unsigned* __restrict__ bufS,
                        const float* __restrict__ gcn_w1, const float* __restrict__ gcn_w2,
                        const float* __restrict__ gat_w1, const float* __restrict__ gat_w2,
                        __half* __restrict__ wPackC, __half* __restrict__ wPackG){
    int t = threadIdx.x;
    if (blockIdx.x >= 910) {
        // one-time f16 weight packing in EXACT k_l1m LDS layout: [W2T 64x72 | W1T 64x40]
        const float* W1 = (blockIdx.x == 910) ? gcn_w1 : gat_w1;
        const float* W2 = (blockIdx.x == 910) ? gcn_w2 : gat_w2;
        __half* wp = (blockIdx.x == 910) ? wPackC : wPackG;
        int D = (blockIdx.x == 910) ? DM : DP;
        for (int i = t; i < 4608; i += 256) {
            int colj = i / 72, k = i - colj * 72;
            wp[i] = __float2half(k < 64 ? W2[k * 64 + colj] : 0.f);
        }
        for (int i = t; i < 2560; i += 256) {
            int colj = i / 40, k = i - colj * 40;
            wp[4608 + i] = __float2half(k < D ? W1[k * 64 + colj] : 0.f);
        }
        return;
    }
    __shared__ int lh[512];
    __shared__ int lbase[512];
    const int* ei; int* cursor; unsigned* buf; int E, K, base, sw, STR;
    if (blockIdx.x < 128)      { ei = eiM; cursor = cursorM; buf = bufM; E = EM; K = 512; base = blockIdx.x * 4096; sw = 0; STR = MSTR; }
    else if (blockIdx.x < 519) { ei = eiP; cursor = cursorP; buf = bufP; E = EP; K = 391; base = (blockIdx.x - 128) * 4096; sw = 0; STR = PSTR; }
    else                       { ei = eiP; cursor = cursorS; buf = bufS; E = EP; K = 391; base = (blockIdx.x - 519) * 4096; sw = 1; STR = PSTR; }
    for (int i = t; i < K; i += 256) lh[i] = 0;
    __syncthreads();
    int end = min(base + 4096, E);
    unsigned pay[16]; int bslot[16];
    int cnt = 0;
    for (int e = base + t; e < end; e += 256) {
        int u = ei[e], v = ei[E + e];
        int key = sw ? u : v, oth = sw ? v : u;
        int b = key >> 8;
        int ls = atomicAdd(&lh[b], 1);
        pay[cnt] = ((unsigned)(key & 255) << 24) | (unsigned)oth;
        bslot[cnt] = (b << 13) | ls;
        cnt++;
    }
    __syncthreads();
    for (int i = t; i < K; i += 256)
        lbase[i] = lh[i] ? atomicAdd(&cursor[i], lh[i]) : 0;
    __syncthreads();
    for (int j = 0; j < cnt; j++) {
        int b = bslot[j] >> 13, ls = bslot[j] & 8191;
        int pos = lbase[b] + ls;
        if (pos < STR)                          // overflow guard (16-sigma margin, never hit)
            buf[(size_t)b * STR + pos] = pay[j];
    }
}

// fine pass (fixed-stride buckets) + fused prep epilogue
__global__ void k_fine2(const unsigned* __restrict__ bufM, const int* __restrict__ cntM,
                        int* __restrict__ molRP, int* __restrict__ molCOL, float* __restrict__ dinv,
                        const unsigned* __restrict__ bufP, const int* __restrict__ cntP,
                        int* __restrict__ protRP, int* __restrict__ protCOL,
                        const unsigned* __restrict__ bufS, const int* __restrict__ cntS,
                        int* __restrict__ srcRP, int* __restrict__ srcCOL,
                        const float* __restrict__ mol_x, __half* __restrict__ x8,
                        const int* __restrict__ batch, int* __restrict__ gstart,
                        int* __restrict__ gend,
                        const float* __restrict__ prot_x, const float* __restrict__ W1a,
                        const float* __restrict__ as_, const float* __restrict__ ad_,
                        __half* __restrict__ x32, float* __restrict__ es,
                        float* __restrict__ ed_){
    __shared__ float vas[20], vds[20];
    int t = threadIdx.x;
    int k; const unsigned* buf; const int* cntA; int* rp; int* col; int n, OB, dv, pp, STR;
    if (blockIdx.x < 512)      { k = blockIdx.x;       buf = bufM; cntA = cntM; rp = molRP;  col = molCOL;  n = NM; OB = 20; dv = 1; pp = 0; STR = MSTR; }
    else if (blockIdx.x < 903) { k = blockIdx.x - 512; buf = bufP; cntA = cntP; rp = protRP; col = protCOL; n = NP; OB = 21; dv = 0; pp = 1; STR = PSTR; }
    else                       { k = blockIdx.x - 903; buf = bufS; cntA = cntS; rp = srcRP;  col = srcCOL;  n = NP; OB = 21; dv = 0; pp = 0; STR = PSTR; }
    if (pp) {
        if (t < 20) {
            float s = 0.f;
            for (int j = 0; j < 64; j++) s += W1a[t * 64 + j] * as_[j];
            vas[t] = s;
        } else if (t >= 32 && t < 52) {
            int kk = t - 32;
            float s = 0.f;
            for (int j = 0; j < 64; j++) s += W1a[kk * 64 + j] * ad_[j];
            vds[kk] = s;
        }
    }
    int start = k * STR;
    int end = start + min(cntA[k], STR);
    __shared__ int cnt[256];
    __shared__ int cur[256];
    cnt[t] = 0;
    __syncthreads();
    for (int p = start + t; p < end; p += 256)
        atomicAdd(&cnt[buf[p] >> 24], 1);
    __syncthreads();
    int v0 = cnt[t];
    int lane = t & 63, wid = t >> 6;
    int v = v0;
    #pragma unroll
    for (int off = 1; off < 64; off <<= 1) {
        int x = __shfl_up(v, off, 64);
        if (lane >= off) v += x;
    }
    __shared__ int ws[4];
    if (lane == 63) ws[wid] = v;
    __syncthreads();
    int add = 0;
    for (int w = 0; w < wid; w++) add += ws[w];
    int excl = v + add - v0;
    int ofs = start + excl;
    cur[t] = ofs;
    int idx = (k << 8) + t;
    if (idx < n) {
        rp[idx] = (int)((unsigned)ofs | ((unsigned)v0 << OB));
        if (dv) dinv[idx] = rsqrtf((float)(v0 + 1));
    }
    __syncthreads();
    for (int p = start + t; p < end; p += 256) {
        unsigned pk = buf[p];
        int slot = atomicAdd(&cur[pk >> 24], 1);
        col[slot] = (int)(pk & 0xFFFFFFu);
    }
    // ---- fused prep epilogue ----
    if (dv) {
        float dd = rsqrtf((float)(v0 + 1));
        H8 r;
        #pragma unroll
        for (int kk = 0; kk < 3; kk++)
            r.h2[kk] = __floats2half2_rn(dd * mol_x[idx*6 + 2*kk], dd * mol_x[idx*6 + 2*kk + 1]);
        r.h2[3] = __floats2half2_rn(0.f, 0.f);
        *(float4*)&x8[(size_t)idx * 8] = r.f4;
        int g = batch[idx];
        if (idx == 0 || batch[idx - 1] != g) gstart[g] = idx;
        if (idx == NM - 1 || batch[idx + 1] != g) gend[g] = idx + 1;
    } else if (pp && idx < n) {
        float xv[20];
        float s = 0.f, d = 0.f;
        #pragma unroll
        for (int kk = 0; kk < 20; kk++) {
            xv[kk] = prot_x[idx*20 + kk];
            s += xv[kk] * vas[kk]; d += xv[kk] * vds[kk];
        }
        es[idx] = s; ed_[idx] = d;
        H8 r0, r1, r2, rz;
        #pragma unroll
        for (int kk = 0; kk < 4; kk++) r0.h2[kk] = __floats2half2_rn(xv[2*kk],   xv[2*kk+1]);
        #pragma unroll
        for (int kk = 0; kk < 4; kk++) r1.h2[kk] = __floats2half2_rn(xv[8+2*kk], xv[9+2*kk]);
        r2.h2[0] = __floats2half2_rn(xv[16], xv[17]);
        r2.h2[1] = __floats2half2_rn(xv[18], xv[19]);
        r2.h2[2] = __floats2half2_rn(0.f, 0.f);
        r2.h2[3] = __floats2half2_rn(0.f, 0.f);
        rz.h2[0] = rz.h2[1] = rz.h2[2] = rz.h2[3] = __floats2half2_rn(0.f, 0.f);
        *(float4*)&x32[(size_t)idx * 32]      = r0.f4;
        *(float4*)&x32[(size_t)idx * 32 + 8]  = r1.f4;
        *(float4*)&x32[(size_t)idx * 32 + 16] = r2.f4;
        *(float4*)&x32[(size_t)idx * 32 + 24] = rz.f4;
    }
}

// ================= fused L1 gather + MLP (MFMA f16 16x16x32), 64 nodes/block, 4 waves =====
// LDS overlay (halves): W2T [64][72] @0, W1T [64][40] @4608, Ain [4][16][40] @7168,
//                       X1 [4][16][72] @4608 (overlays W1T+Ain after both are dead).
// 19456 B -> 8 blocks/CU. Weights staged by float4 copy from pre-packed global blob.
// Edge loops unrolled x2 with dual in-flight loads (latency-bound gather: double MLP).
template<int D, int ATT, int SCALE>
__device__ __forceinline__ void l1m_body(__half* smemh, int bid, int tid,
                                         const int* __restrict__ rp, const int* __restrict__ col,
                                         const __half* __restrict__ xrow,
                                         const float* __restrict__ es1, const float* __restrict__ ed1,
                                         const __half* __restrict__ wPack, const float* __restrict__ b1,
                                         const float* __restrict__ as_, const float* __restrict__ ad_,
                                         __half* __restrict__ hout, float* __restrict__ esO,
                                         float* __restrict__ edO, const float* __restrict__ dinv,
                                         int n){
    __half* W2Ts = smemh;            // 4608 halves @0
    __half* W1Ts = smemh + 4608;     // 2560 halves @4608
    __half* AinS = smemh + 7168;     // 2560 halves @7168 (4 waves * 640)
    __half* X1S  = smemh + 4608;     // 4608 halves overlay @4608
    int lane = tid & 63, w = tid >> 6;
    int c = lane & 15, g = lane >> 4;
    int node0 = bid * 64 + w * 16;

    // ---- stage packed weights: 7168 halves = 896 float4, coalesced, conflict-free ----
    {
        const float4* wp4 = (const float4*)wPack;
        float4* sm4 = (float4*)smemh;
        #pragma unroll
        for (int i = 0; i < 3; i++) sm4[tid + 256 * i] = wp4[tid + 256 * i];
        if (tid < 128) sm4[768 + tid] = wp4[768 + tid];
    }
    // ---- zero own wave's AinS slab ----
    {
        float4 z4 = make_float4(0.f, 0.f, 0.f, 0.f);
        float4* az = (float4*)(AinS + w * 640);
        for (int i = lane; i < 80; i += 64) az[i] = z4;
    }

    // ---- L1 gather straight into AinS ----
    if (!ATT) {
        // mol GCN: 16 nodes/wave, 4 lanes/node (edge slots); deg~4 -> single iteration
        int nd = lane >> 2, q = lane & 3;
        int node = node0 + nd;
        unsigned pk = (unsigned)rp[node];
        int s0 = (int)(pk & 0xFFFFFu);
        int deg = (int)(pk >> 20);
        float acc[6] = {0.f,0.f,0.f,0.f,0.f,0.f};
        if (q == 0) {
            HF8 r; r.f4 = *(const float4*)&xrow[(size_t)node * 8];
            #pragma unroll
            for (int i = 0; i < 6; i++) acc[i] = (float)r.h[i];
        }
        for (int base = 0; base < deg; base += 8) {
            int sA = base + q, sB = base + q + 4;
            bool vA = sA < deg, vB = sB < deg;
            int uA = vA ? col[s0 + sA] : node;
            int uB = vB ? col[s0 + sB] : node;
            HF8 rA, rB;
            rA.f4 = *(const float4*)&xrow[(size_t)uA * 8];
            rB.f4 = *(const float4*)&xrow[(size_t)uB * 8];
            float wA = vA ? 1.f : 0.f, wB = vB ? 1.f : 0.f;
            #pragma unroll
            for (int i = 0; i < 6; i++) acc[i] += wA * (float)rA.h[i] + wB * (float)rB.h[i];
        }
        #pragma unroll
        for (int m = 1; m < 4; m <<= 1) {
            #pragma unroll
            for (int i = 0; i < 6; i++) acc[i] += __shfl_xor(acc[i], m, 64);
        }
        if (q == 0) {
            float dd = dinv[node];
            #pragma unroll
            for (int k = 0; k < 6; k++)
                AinS[w * 640 + nd * 40 + k] = __float2half(dd * acc[k]);
        }
    } else {
        // prot GAT: 4 rounds of {4 nodes x (4 slots x 4 chunks)}; chunk 3 dead (zero-pad).
        // Edge loop unrolled x2: dual col/es/row loads in flight per iteration.
        int nd4 = lane >> 4;
        int slot = (lane >> 2) & 3;
        int chunk = lane & 3;
        bool live = chunk < 3;
        for (int rr = 0; rr < 4; rr++) {
            int row = rr * 4 + nd4;
            int node = node0 + row;
            bool valid = node < n;
            int nodeC = valid ? node : 0;
            unsigned pk = (unsigned)rp[nodeC];
            int s0 = (int)(pk & 0x1FFFFFu);
            int deg = valid ? (int)(pk >> 21) : 0;
            float edv = ed1[nodeC];
            float selfw = __expf(leaky(es1[nodeC] + edv));
            float acc[8] = {0.f,0.f,0.f,0.f,0.f,0.f,0.f,0.f};
            float den = (slot == 0) ? selfw : 0.f;
            if (slot == 0 && valid && live) {
                HF8 r; r.f4 = *(const float4*)&xrow[(size_t)node * 32 + (chunk << 3)];
                #pragma unroll
                for (int i = 0; i < 8; i++) acc[i] = selfw * (float)r.h[i];
            }
            for (int base = 0; base < deg; base += 8) {
                int sA = base + slot, sB = base + slot + 4;
                bool vA = sA < deg, vB = sB < deg;
                int uA = vA ? col[s0 + sA] : nodeC;
                int uB = vB ? col[s0 + sB] : nodeC;
                float eA = es1[uA], eB = es1[uB];
                HF8 rA, rB;
                if (live) {
                    rA.f4 = *(const float4*)&xrow[(size_t)uA * 32 + (chunk << 3)];
                    rB.f4 = *(const float4*)&xrow[(size_t)uB * 32 + (chunk << 3)];
                }
                float wA = vA ? __expf(leaky(eA + edv)) : 0.f;
                float wB = vB ? __expf(leaky(eB + edv)) : 0.f;
                if (live) {
                    #pragma unroll
                    for (int i = 0; i < 8; i++)
                        acc[i] += wA * (float)rA.h[i] + wB * (float)rB.h[i];
                }
                den += wA + wB;
            }
            #pragma unroll
            for (int m = 4; m <= 8; m <<= 1) {
                #pragma unroll
                for (int i = 0; i < 8; i++) acc[i] += __shfl_xor(acc[i], m, 64);
                den += __shfl_xor(den, m, 64);
            }
            float inv = 1.f / den;
            if (slot == 0 && valid && live) {
                #pragma unroll
                for (int i = 0; i < 8; i++) {
                    int k = (chunk << 3) + i;
                    if (k < 20) AinS[w * 640 + row * 40 + k] = __float2half(acc[i] * inv);
                }
            }
        }
    }
    __syncthreads();   // gather + weight staging complete

    // ---- layer 1: register-cache A and all W1T fragments, then sync, then MFMA+X1 write ----
    f32x4 zz = {0.f, 0.f, 0.f, 0.f};
    f16x8 a1 = *(const f16x8*)&AinS[w * 640 + c * 40 + 8 * g];
    f16x8 b1f[4];
    #pragma unroll
    for (int t = 0; t < 4; t++)
        b1f[t] = *(const f16x8*)&W1Ts[(16 * t + c) * 40 + 8 * g];
    __syncthreads();   // all W1Ts/AinS reads done -> X1S overlay may be written
    #pragma unroll
    for (int t = 0; t < 4; t++) {
        f32x4 h = __builtin_amdgcn_mfma_f32_16x16x32_f16(a1, b1f[t], zz, 0, 0, 0);
        float bv = b1[16 * t + c];
        #pragma unroll
        for (int r = 0; r < 4; r++) {
            float v = fmaxf(h[r] + bv, 0.f);
            X1S[w * 1152 + (4 * g + r) * 72 + 16 * t + c] = __float2half(v);
        }
    }
    // X1S slabs are wave-local: no block sync needed before layer 2

    // ---- layer 2 ----
    f32x4 acc2[4];
    #pragma unroll
    for (int t = 0; t < 4; t++) acc2[t] = zz;
    #pragma unroll
    for (int kt = 0; kt < 2; kt++) {
        f16x8 a = *(const f16x8*)&X1S[w * 1152 + c * 72 + 32 * kt + 8 * g];
        #pragma unroll
        for (int t = 0; t < 4; t++) {
            f16x8 b = *(const f16x8*)&W2Ts[(16 * t + c) * 72 + 32 * kt + 8 * g];
            acc2[t] = __builtin_amdgcn_mfma_f32_16x16x32_f16(a, b, acc2[t], 0, 0, 0);
        }
    }

    if (ATT) {
        float asv[4], adv[4];
        #pragma unroll
        for (int t = 0; t < 4; t++) { asv[t] = as_[16 * t + c]; adv[t] = ad_[16 * t + c]; }
        #pragma unroll
        for (int r = 0; r < 4; r++) {
            float xa = 0.f, ya = 0.f;
            #pragma unroll
            for (int t = 0; t < 4; t++) { xa += acc2[t][r] * asv[t]; ya += acc2[t][r] * adv[t]; }
            #pragma unroll
            for (int m = 1; m < 16; m <<= 1) { xa += __shfl_xor(xa, m, 16); ya += __shfl_xor(ya, m, 16); }
            int nd = node0 + 4 * g + r;
            if (c == 0 && nd < n) { esO[nd] = xa; edO[nd] = ya; }
        }
    }
    if (SCALE) {
        #pragma unroll
        for (int r = 0; r < 4; r++) {
            float dd = dinv[node0 + 4 * g + r];
            #pragma unroll
            for (int t = 0; t < 4; t++) acc2[t][r] *= dd;
        }
    }

    // ---- repack through X1S (wave-local) -> coalesced float4 f16 stores ----
    #pragma unroll
    for (int t = 0; t < 4; t++) {
        #pragma unroll
        for (int r = 0; r < 4; r++)
            X1S[w * 1152 + (4 * g + r) * 72 + 16 * t + c] = __float2half(acc2[t][r]);
    }
    int rr2 = lane >> 2, seg = lane & 3;
    union { f16x8 h; float4 f; } o;
    o.h = *(const f16x8*)&X1S[w * 1152 + rr2 * 72 + seg * 16];
    int nd = node0 + rr2;
    if (!ATT || nd < n)
        *(float4*)&hout[(size_t)nd * 64 + seg * 16] = o.f;
}

#define PROTB 1563   // cdiv(NP, 64)

__global__ __launch_bounds__(256, 8)
void k_l1m(const int* __restrict__ molRP, const int* __restrict__ molCOL,
           const __half* __restrict__ x8, const float* __restrict__ dinvM,
           const __half* __restrict__ wPackC, const float* __restrict__ gcn_b1,
           __half* __restrict__ h2hM,
           const int* __restrict__ protRP, const int* __restrict__ protCOL,
           const __half* __restrict__ x32, const float* __restrict__ es1,
           const float* __restrict__ ed1,
           const __half* __restrict__ wPackG, const float* __restrict__ gat_b1,
           const float* __restrict__ as2, const float* __restrict__ ad2,
           __half* __restrict__ h2hP, float* __restrict__ es2, float* __restrict__ ed2){
    __shared__ __attribute__((aligned(16))) __half smemh[9728];   // 19456 B -> 8 blocks/CU
    if (blockIdx.x < PROTB)   // long prot blocks first (LPT)
        l1m_body<20, 1, 0>(smemh, blockIdx.x, threadIdx.x, protRP, protCOL, x32, es1, ed1,
                           wPackG, gat_b1, as2, ad2,
                           h2hP, es2, ed2, nullptr, NP);
    else
        l1m_body<6, 0, 1>(smemh, blockIdx.x - PROTB, threadIdx.x, molRP, molCOL, x8, nullptr, nullptr,
                          wPackC, gcn_b1, nullptr, nullptr,
                          h2hM, nullptr, nullptr, dinvM, NM);
}

// ================= prot den (dst-CSR, es2-only gather) =================
__global__ void k_den(const int* __restrict__ protRP, const int* __restrict__ protCOL,
                      const float* __restrict__ es, const float* __restrict__ ed_,
                      float2* __restrict__ denEd){
    int tid = threadIdx.x;
    int node = (blockIdx.x << 4) + (tid >> 4);
    int l16 = tid & 15;
    unsigned pk = (unsigned)protRP[node];
    int s0 = (int)(pk & 0x1FFFFFu);
    int deg = (int)(pk >> 21);
    float edv = ed_[node];
    float den = 0.f;
    for (int s = l16; s < deg; s += 16) {
        int u = protCOL[s0 + s];
        den += __expf(leaky(es[u] + edv));
    }
    #pragma unroll
    for (int m = 1; m < 16; m <<= 1) den += __shfl_xor(den, m, 16);
    if (l16 == 0) {
        float selfw = __expf(leaky(es[node] + edv));
        denEd[node] = make_float2(1.f / (den + selfw), edv);
    }
}

// ================= merged L2: mol gather+pool (8192 blocks) + prot coef*row sum (3125 blocks) ==
__global__ void k_l2c(const int* __restrict__ molRP, const int* __restrict__ molCOL,
                      const __half* __restrict__ hhM, const float* __restrict__ dinv,
                      const int* __restrict__ batch, float* __restrict__ gsum,
                      const int* __restrict__ srcRP, const int* __restrict__ srcCOL,
                      const float* __restrict__ es, const float2* __restrict__ denEd,
                      const __half* __restrict__ hhP, float* __restrict__ psumP){
    __shared__ float sb[16][64];
    __shared__ int gidS[16];
    int tid = threadIdx.x;
    if (blockIdx.x < NM/16) {
        // mol L2: 16 nodes/block, 4 nodes/wave; 2 edge-slots x 8 feature-chunks, unroll x2
        int bid = blockIdx.x;
        int wv = tid >> 6, l = tid & 63;
        int nd = l >> 4;
        int slot = (l >> 3) & 1;
        int q = l & 7;
        int node = (bid << 4) + (wv << 2) + nd;
        int row = (wv << 2) + nd;
        unsigned pk = (unsigned)molRP[node];
        int s0 = (int)(pk & 0xFFFFFu);
        int deg = (int)(pk >> 20);
        float acc[8] = {0.f,0.f,0.f,0.f,0.f,0.f,0.f,0.f};
        if (slot == 0) {
            HF8 r; r.f4 = *(const float4*)&hhM[(size_t)node * 64 + (q << 3)];
            #pragma unroll
            for (int i = 0; i < 8; i++) acc[i] = (float)r.h[i];
        }
        for (int base = 0; base < deg; base += 4) {
            int sA = base + slot, sB = base + slot + 2;
            bool vA = sA < deg, vB = sB < deg;
            int uA = vA ? molCOL[s0 + sA] : node;
            int uB = vB ? molCOL[s0 + sB] : node;
            HF8 rA, rB;
            rA.f4 = *(const float4*)&hhM[(size_t)uA * 64 + (q << 3)];
            rB.f4 = *(const float4*)&hhM[(size_t)uB * 64 + (q << 3)];
            float wA = vA ? 1.f : 0.f, wB = vB ? 1.f : 0.f;
            #pragma unroll
            for (int i = 0; i < 8; i++) acc[i] += wA * (float)rA.h[i] + wB * (float)rB.h[i];
        }
        #pragma unroll
        for (int i = 0; i < 8; i++) acc[i] += __shfl_xor(acc[i], 8, 64);
        if (slot == 0) {
            float sc = dinv[node];
            #pragma unroll
            for (int i = 0; i < 8; i++) sb[row][(q << 3) + i] = acc[i] * sc;
        }
        if (l == (nd << 4)) gidS[row] = batch[node];
        __syncthreads();
        if (tid < 64) {
            int i = 0;
            while (i < 16) {
                int g0 = gidS[i];
                float s = sb[i][tid];
                int j = i + 1;
                while (j < 16 && gidS[j] == g0) { s += sb[j][tid]; j++; }
                atomicAdd(&gsum[(g0 << 6) + tid], s);
                i = j;
            }
        }
    } else {
        // prot: per-source coef gather (unroll x2) + coalesced weighted row accumulate
        int cb = blockIdx.x - NM/16;
        int wv = tid >> 6, l = tid & 63;
        int node = cb * 32 + (tid >> 3);
        int l8 = tid & 7;
        unsigned pk = (unsigned)srcRP[node];
        int s0 = (int)(pk & 0x1FFFFFu);
        int deg = (int)(pk >> 21);
        float esu = es[node];
        float sum = 0.f;
        for (int base = 0; base < deg; base += 16) {
            int sA = base + l8, sB = base + l8 + 8;
            bool vA = sA < deg, vB = sB < deg;
            int uA = vA ? srcCOL[s0 + sA] : node;
            int uB = vB ? srcCOL[s0 + sB] : node;
            float2 dA = denEd[uA], dB = denEd[uB];
            float wA = vA ? __expf(leaky(esu + dA.y)) * dA.x : 0.f;
            float wB = vB ? __expf(leaky(esu + dB.y)) * dB.x : 0.f;
            sum += wA + wB;
        }
        #pragma unroll
        for (int m = 1; m < 8; m <<= 1) sum += __shfl_xor(sum, m, 8);
        float2 du = denEd[node];
        float coef = __expf(leaky(esu + du.y)) * du.x + sum;
        HF8 r; r.f4 = *(const float4*)&hhP[(size_t)node * 64 + (l8 << 3)];
        float acc[8];
        #pragma unroll
        for (int i = 0; i < 8; i++) acc[i] = coef * (float)r.h[i];
        #pragma unroll
        for (int m = 8; m <= 32; m <<= 1) {
            #pragma unroll
            for (int i = 0; i < 8; i++) acc[i] += __shfl_xor(acc[i], m, 64);
        }
        if ((l >> 3) == 0) {
            #pragma unroll
            for (int i = 0; i < 8; i++) sb[wv][(l8 << 3) + i] = acc[i];
        }
        __syncthreads();
        if (tid < 64) {
            float s = sb[0][tid] + sb[1][tid] + sb[2][tid] + sb[3][tid];
            atomicAdd(&psumP[((cb & 63) << 6) + tid], s);
        }
    }
}

// ---------------- fused classifier (reduces psumP, applies layer-2 biases) ----------------
__global__ void k_cls(const float* __restrict__ gsum, const int* __restrict__ gstart,
                      const int* __restrict__ gend, const float* __restrict__ psumP,
                      const float* __restrict__ bg, const float* __restrict__ bp,
                      const float* __restrict__ W1, const float* __restrict__ b1,
                      const float* __restrict__ w2, const float* __restrict__ b2,
                      float* __restrict__ out){
    __shared__ float W1s[128 * 64];
    __shared__ float pv[64], bgs[64];
    int tid = threadIdx.x;
    for (int k = tid; k < 128 * 64; k += 256) W1s[k] = W1[k];
    if (tid < 64) {
        float s = 0.f;
        for (int sl = 0; sl < 64; sl++) s += psumP[(sl << 6) + tid];
        pv[tid] = s * (1.0f / (float)NP) + bp[tid];
        bgs[tid] = bg[tid];
    }
    __syncthreads();
    int g = blockIdx.x * 4 + (tid >> 6);
    int j = tid & 63;
    float cntf = (float)(gend[g] - gstart[g]);
    float inv = 1.0f / fmaxf(cntf, 1.0f);
    float acc = b1[j];
    #pragma unroll 8
    for (int k = 0; k < 64; k++) acc += (gsum[g * 64 + k] * inv + bgs[k]) * W1s[k * 64 + j];
    #pragma unroll 8
    for (int k = 0; k < 64; k++) acc += pv[k] * W1s[(64 + k) * 64 + j];
    float v = fmaxf(acc, 0.f) * w2[j];
    #pragma unroll
    for (int off = 32; off > 0; off >>= 1) v += __shfl_down(v, off, 64);
    if (j == 0) out[g] = 1.0f / (1.0f + expf(-(v + b2[0])));
}

extern "C" void kernel_launch(void* const* d_in, const int* in_sizes, int n_in,
                              void* d_out, int out_size, void* d_ws, size_t ws_size,
                              hipStream_t stream) {
    const float* mol_x   = (const float*)d_in[0];
    const int*   mol_ei  = (const int*)d_in[1];
    const int*   mol_bat = (const int*)d_in[2];
    const float* prot_x  = (const float*)d_in[3];
    const int*   prot_ei = (const int*)d_in[4];
    const float* gcn_w1  = (const float*)d_in[5];
    const float* gcn_b1  = (const float*)d_in[6];
    const float* gcn_w2  = (const float*)d_in[7];
    const float* gcn_b2  = (const float*)d_in[8];
    const float* gat_w1  = (const float*)d_in[9];
    const float* gat_as1 = (const float*)d_in[10];
    const float* gat_ad1 = (const float*)d_in[11];
    const float* gat_b1  = (const float*)d_in[12];
    const float* gat_w2  = (const float*)d_in[13];
    const float* gat_as2 = (const float*)d_in[14];
    const float* gat_ad2 = (const float*)d_in[15];
    const float* gat_b2  = (const float*)d_in[16];
    const float* cls_w1  = (const float*)d_in[17];
    const float* cls_b1  = (const float*)d_in[18];
    const float* cls_w2  = (const float*)d_in[19];
    const float* cls_b2  = (const float*)d_in[20];
    float* out = (float*)d_out;

    float* ws_f = (float*)d_ws;

    // ---- persistent tail ----
    float* T       = ws_f + 16777216;
    float* gsum    = T;                       // 262,144 floats (zeroed)
    int*   gstart  = (int*)(T + 262144);      // 4,096 (zeroed)
    int*   gend    = (int*)(T + 266240);      // 4,096 (zeroed)
    int*   cursorM = (int*)(T + 270400);      // 512 (zeroed; bucket counters)
    int*   cursorP = (int*)(T + 270912);      // 512 (zeroed)
    int*   cursorS = (int*)(T + 271424);      // 512 (zeroed)
    float* psumP   = T + 273474;              // 64x64 (zeroed)
    __half* wPackC = (__half*)(T + 279200);   // 7168 halves
    __half* wPackG = (__half*)(T + 282784);   // 7168 halves -> ends T+286,368

    // ---- fixed-stride bucket staging (dead after k_fine2) ----
    unsigned* bufM = (unsigned*)ws_f;                    // 512*1536  = [0, 786,432)
    unsigned* bufP = (unsigned*)(ws_f + 786432);         // 391*5120  = [786,432, 2,788,352)
    unsigned* bufS = (unsigned*)(ws_f + 2788352);        // 391*5120  = [2,788,352, 4,790,272)

    // ---- overlapping phase regions (offsets in floats) ----
    __half*   h2hP      = (__half*)ws_f;
    int*      srcCOL    = (int*)(ws_f + 4790400);        // 391*5120 -> ends 6,792,320
    float*    es2       = ws_f + 6792320;
    float*    ed2       = ws_f + 6892320;
    float2*   denEd     = (float2*)(ws_f + 6992320);     // 2*NP -> ends 7,192,320
    int*      srcRP     = (int*)(ws_f + 7192320);        // NP -> 7,292,320
    float*    es1       = ws_f + 7292352;                // NP -> 7,392,352
    float*    ed1       = ws_f + 7392384;                // NP -> 7,492,384
    __half*   h2hM      = (__half*)(ws_f + 8388608);     // NM*64 halves -> 12,582,912
    int*      molCOL    = (int*)(ws_f + 12582912);       // 512*1536 -> 13,369,344 (+pad)
    int*      molRP     = (int*)(ws_f + 13369408);       // NM -> 13,500,480
    float*    dinvM     = ws_f + 13500480;               // NM -> 13,631,552
    __half*   x8h       = (__half*)(ws_f + 13631552);    // NM*8 halves -> 14,155,840
    int*      protCOL   = (int*)(ws_f + 14155840);       // 391*5120 -> 16,157,760
    int*      protRP    = (int*)(ws_f + 16157760);       // NP -> 16,257,760 (< T=16,777,216)
    __half*   x32h      = (__half*)(ws_f + 17100000);    // NP*32 halves -> 18,700,000

    // single upfront zero of gsum..psumP+cursors (contiguous tail region)
    (void)hipMemsetAsync(gsum, 0, (size_t)279169 * sizeof(float), stream);

    // ================= single-pass bucketed partition (+ weight packing blocks) ==========
    k_part2<<<912, 256, 0, stream>>>(mol_ei, cursorM, bufM, prot_ei, cursorP, bufP,
                                     cursorS, bufS,
                                     gcn_w1, gcn_w2, gat_w1, gat_w2, wPackC, wPackG);
    // fine pass + fused prep epilogue
    k_fine2<<<512 + 391 + 391, 256, 0, stream>>>(bufM, cursorM, molRP, molCOL, dinvM,
                                                 bufP, cursorP, protRP, protCOL,
                                                 bufS, cursorS, srcRP, srcCOL,
                                                 mol_x, x8h, mol_bat, gstart, gend,
                                                 prot_x, gat_w1, gat_as1, gat_ad1,
                                                 x32h, es1, ed1);

    // ================= fused L1 gather + MLP (prot-first LPT order) =================
    k_l1m<<<PROTB + NM/64, 256, 0, stream>>>(molRP, molCOL, x8h, dinvM,
                                             wPackC, gcn_b1, h2hM,
                                             protRP, protCOL, x32h, es1, ed1,
                                             wPackG, gat_b1, gat_as2, gat_ad2,
                                             h2hP, es2, ed2);

    // ================= L2 phase: prot den -> (mol gather+pool || prot coef*row sum) =========
    k_den<<<NP/16, 256, 0, stream>>>(protRP, protCOL, es2, ed2, denEd);
    k_l2c<<<NM/16 + NP/32, 256, 0, stream>>>(molRP, molCOL, h2hM, dinvM, mol_bat, gsum,
                                             srcRP, srcCOL, es2, denEd, h2hP, psumP);

    // ================= classifier (reduces psumP, applies layer-2 biases) =================
    k_cls<<<NG/4, 256, 0, stream>>>(gsum, gstart, gend, psumP, gcn_b2, gat_b2,
                                    cls_w1, cls_b1, cls_w2, cls_b2, out);
}